// Round 16
// baseline (1681.373 us; speedup 1.0000x reference)
//
#include <hip/hip_runtime.h>
#include <cstdint>
#include <cstddef>

typedef _Float16 h8 __attribute__((ext_vector_type(8)));
typedef _Float16 h4 __attribute__((ext_vector_type(4)));
typedef float    f32x4 __attribute__((ext_vector_type(4)));

#define B_   2
#define P_   8192
#define NVOX 24
#define N3   13824

// ---- workspace layout (bytes). Peak < 63.5 MB. ----
// conv:  meshS@0 m16@14.2M h1cl@28.3M Wb/Wb2c@44.7M ; conv2 slabs h2p@0 (25.2M)
// prim:  h2cl@39.85M (8.4M) ; img@0 (<=38.3M, over dead h2p/h1cl) ;
//        p_part@48.23M (8.4M) ; pr1@56.62M (1M)
// dec:   Wbd@0 (10.6M) d2h@10.6M (28.3M) d1cl@41.3M (1.8M, over dead h2cl)
#define MESHS_OFF 0ull
#define M16_OFF   14155776ull
#define H1CL_OFF  28311552ull
#define WB_OFF    44695552ull
#define WB2C_OFF  44695552ull
#define H2P_OFF   0ull
#define IMG_OFF   0ull
#define H2CL_OFF  39845888ull
#define PPART_OFF 48234496ull
#define PR1_OFF   56623104ull
#define WBD_OFF   0ull
#define D2H_OFF   10616832ull
#define D1CL_OFF  41287680ull
#define VID_OFF   63504384ull
#define UBUF_OFF  63700992ull
#define SBUF_OFF  63832064ull
#define VBUF_OFF  63857664ull

#define M16_PL   3538944ull     // mesh16 plane stride (elements)
#define H1_PL    4096000ull     // h1cl plane stride (elements)
#define H2CL_PL  2097152ull     // h2cl plane stride (elements)
#define D1_PL    442368ull      // d1cl plane stride (elements)

// ---------------- helpers ----------------
__device__ inline void split2(float x, _Float16& a0, _Float16& a1)
{
    a0 = (_Float16)x;
    float r = x - (float)a0;
    a1 = (_Float16)(r * 2048.0f);
}

__device__ inline void gload16(const void* g, void* l)
{
    __builtin_amdgcn_global_load_lds(
        (const __attribute__((address_space(1))) char*)g,
        (__attribute__((address_space(3))) char*)l, 16, 0, 0);
}

// parity-class helpers for dec2
__device__ inline void tapDecode(int cls, int ti, int& kd, int& kh, int& kw)
{
    int px = (cls >> 2) & 1, py = (cls >> 1) & 1, pz = cls & 1;
    int tiz = pz ? (ti & 1) : 0;
    int t1  = ti >> pz;
    int tiy = py ? (t1 & 1) : 0;
    int tix = t1 >> py;
    kd = px ? tix*2 : 1;
    kh = py ? tiy*2 : 1;
    kw = pz ? tiz*2 : 1;
}

// ---------------- voxel ids ----------------
__global__ __launch_bounds__(256)
void k_vid(const float* __restrict__ pcl, int* __restrict__ vid)
{
    int b = blockIdx.x;
    const float* pb = pcl + (size_t)b * P_ * 3;
    float mn[3] = {3e38f, 3e38f, 3e38f};
    float mx[3] = {-3e38f, -3e38f, -3e38f};
    for (int p = threadIdx.x; p < P_; p += 256) {
        #pragma unroll
        for (int d = 0; d < 3; ++d) {
            float v = pb[p*3 + d];
            mn[d] = fminf(mn[d], v);
            mx[d] = fmaxf(mx[d], v);
        }
    }
    __shared__ float red[6][256];
    #pragma unroll
    for (int d = 0; d < 3; ++d) { red[d][threadIdx.x] = mn[d]; red[3+d][threadIdx.x] = mx[d]; }
    __syncthreads();
    for (int s = 128; s > 0; s >>= 1) {
        if (threadIdx.x < (unsigned)s) {
            #pragma unroll
            for (int d = 0; d < 3; ++d) {
                red[d][threadIdx.x]   = fminf(red[d][threadIdx.x],   red[d][threadIdx.x + s]);
                red[3+d][threadIdx.x] = fmaxf(red[3+d][threadIdx.x], red[3+d][threadIdx.x + s]);
            }
        }
        __syncthreads();
    }
    float mn0 = red[0][0], mn1 = red[1][0], mn2 = red[2][0];
    float dd0 = red[3][0] - mn0 + 1e-9f;
    float dd1 = red[4][0] - mn1 + 1e-9f;
    float dd2 = red[5][0] - mn2 + 1e-9f;
    for (int p = threadIdx.x; p < P_; p += 256) {
        float fx = (pb[p*3+0] - mn0) / dd0 * 24.0f;
        float fy = (pb[p*3+1] - mn1) / dd1 * 24.0f;
        float fz = (pb[p*3+2] - mn2) / dd2 * 24.0f;
        int ix = (int)floorf(fx); ix = ix < 0 ? 0 : (ix > 23 ? 23 : ix);
        int iy = (int)floorf(fy); iy = iy < 0 ? 0 : (iy > 23 ? 23 : iy);
        int iz = (int)floorf(fz); iz = iz < 0 ? 0 : (iz > 23 ? 23 : iz);
        vid[b*P_ + p] = ix*576 + iy*24 + iz;
    }
}

// ---------------- scatter-add point features -> meshS (B, N3, 128) ----------------
__global__ __launch_bounds__(256)
void k_scatter(const float* __restrict__ feat, const int* __restrict__ vid,
               float* __restrict__ meshS)
{
    int g = blockIdx.x*256 + threadIdx.x;      // B*P*C = 2,097,152
    int c  = g & 127;
    int bp = g >> 7;
    int v  = vid[bp];
    int b  = bp >> 13;
    atomicAdd(&meshS[((size_t)b*N3 + v)*128 + c], feat[g]);
}

// ---------------- mesh fp32 -> fp16x2 limb planes ----------------
__global__ __launch_bounds__(256)
void k_meshsplit(const float* __restrict__ meshS, _Float16* __restrict__ m16)
{
    int g = blockIdx.x*256 + threadIdx.x;   // 884,736 float4 groups
    int e = g*4;
    float4 a = *(const float4*)(meshS + e);
    h4 v0, v1;
    float xs[4] = {a.x, a.y, a.z, a.w};
    #pragma unroll
    for (int j = 0; j < 4; ++j) {
        _Float16 t0, t1; split2(xs[j], t0, t1);
        v0[j] = t0; v1[j] = t1;
    }
    *(h4*)(m16 + e)          = v0;
    *(h4*)(m16 + M16_PL + e) = v1;
}

// ---------------- pre-split conv1 weights ----------------
__global__ __launch_bounds__(256)
void k_splitw1(const float* __restrict__ W, char* __restrict__ Wb)
{
    int g = blockIdx.x*256 + threadIdx.x;   // 4,096,000
    int el   = g & 8191;
    int tile = g >> 13;                      // m*250 + c
    int m = tile / 250, c = tile - m*250;
    int co = el >> 6, kl = el & 63;
    int kg = c*64 + kl;
    int kid = kg >> 7, ci = kg & 127;
    float x = W[((size_t)((m*128 + co)*128 + ci))*125 + kid];
    _Float16 a0, a1; split2(x, a0, a1);
    char* dst = Wb + (size_t)tile*32768 + (co*128 + ((kl*2) ^ ((co&7)<<4)));
    *(_Float16*)(dst)         = a0;
    *(_Float16*)(dst + 16384) = a1;
}

// ---------------- pre-split conv2 weights (half-K at a time) ----------------
__global__ __launch_bounds__(256)
void k_splitw2(const float* __restrict__ W, char* __restrict__ Wb, int cBase, int NC)
{
    int g = blockIdx.x*256 + threadIdx.x;   // 2*NC*8192
    int el   = g & 8191;
    int tile = g >> 13;                      // m*NC + cl
    int m = tile / NC, cl = tile - m*NC;
    int c = cBase + cl;
    int co = el >> 6, kl = el & 63;
    int kg = c*64 + kl;
    int kid = kg >> 8, ci = kg & 255;
    float x = W[((size_t)((m*128 + co)*256 + ci))*125 + kid];
    _Float16 a0, a1; split2(x, a0, a1);
    char* dst = Wb + (size_t)tile*32768 + (co*128 + ((kl*2) ^ ((co&7)<<4)));
    *(_Float16*)(dst)         = a0;
    *(_Float16*)(dst + 16384) = a1;
}

// ---------------- pre-split dec2 weights, PARITY-GROUPED ----------------
__global__ __launch_bounds__(256)
void k_splitwd2p(const float* __restrict__ W, char* __restrict__ Wb)
{
    int g = blockIdx.x*256 + threadIdx.x;   // 216*8192 = 1,769,472
    int el   = g & 8191;
    int tile = g >> 13;                      // mG*54 + chunkG
    int mG = tile / 54, chunkG = tile - mG*54;
    int co = el >> 6, kl = el & 63;
    int rem = chunkG, cls = 0;
    for (int c = 0; c < 8; ++c) {
        int cc = 2 << __popc(c);
        if (rem < cc) { cls = c; break; }
        rem -= cc;
    }
    int k  = rem*64 + kl;
    int ti = k >> 7;
    int ci = k & 127;
    int kd, kh, kw;
    tapDecode(cls, ti, kd, kh, kw);
    int kid = kd*9 + kh*3 + kw;
    float x = W[((size_t)ci*512 + (mG*128 + co))*27 + kid];
    _Float16 a0, a1; split2(x, a0, a1);
    char* dst = Wb + (size_t)tile*32768 + (co*128 + ((kl*2) ^ ((co&7)<<4)));
    *(_Float16*)(dst)         = a0;
    *(_Float16*)(dst + 16384) = a1;
}

// ---------------- prim weight stage: transpose+split into swizzled image ----------------
// W: (256co, 256ci, 729kid). Stage covers kids [kidBase, kidBase+kids).
// chunk (stage-local) = kidlocal*4 + ciseg; image tile = mG*cps4 + chunk.
__global__ __launch_bounds__(256)
void k_wimg(const float* __restrict__ W, char* __restrict__ img,
            int kidBase, int kids, int cps4)
{
    int col = threadIdx.x >> 6;        // 0..3
    int cil = threadIdx.x & 63;
    int coG = blockIdx.y >> 2;         // 0..31
    int ciseg = blockIdx.y & 3;
    int mG = blockIdx.z;
    int co = coG*4 + col;
    int ci = ciseg*64 + cil;
    int kid0 = blockIdx.x * 16;
    const float* src = W + ((size_t)((mG*128 + co)*256) + ci)*729 + kidBase + kid0;
    int wbyte = co*128 + ((cil*2) ^ ((co&7)<<4));
    int nk = min(16, kids - kid0);
    for (int t = 0; t < nk; ++t) {
        float x = src[t];
        _Float16 a0, a1; split2(x, a0, a1);
        char* dst = img + ((size_t)(mG*cps4 + (kid0+t)*4 + ciseg))*32768 + wbyte;
        *(_Float16*)(dst)         = a0;
        *(_Float16*)(dst + 16384) = a1;
    }
}

// ---------------- conv1 MFMA (proven r12 structure) ----------------
__global__ __launch_bounds__(256, 3)
void k_conv1(const _Float16* __restrict__ m16, const char* __restrict__ Wb,
             const float* __restrict__ bias, _Float16* __restrict__ h1cl)
{
    extern __shared__ char lds[];           // A 32KB + B 16KB = 48KB
    const int tid = threadIdx.x;
    const int l   = tid & 63;
    const int w   = tid >> 6;
    const int wm  = w >> 1, wn = w & 1;
    const int n0  = blockIdx.x * 64;
    const int m   = blockIdx.y;

    const _Float16* preP[4];
    #pragma unroll
    for (int i = 0; i < 4; ++i) {
        int g   = w*4096 + i*1024 + l*16;
        int ver = g >> 13;
        int dd  = g & 8191;
        int nl  = dd >> 7;
        int lg  = (dd & 127) ^ ((nl & 7) << 4);
        int klocal = lg >> 1;
        int n  = n0 + nl;
        int b2 = n / 8000;
        int so = n - b2*8000;
        int x = so/400, y = (so/20)%20, z = so%20;
        preP[i] = m16 + (size_t)ver*M16_PL
                      + ((size_t)(b2*13824 + x*576 + y*24 + z))*128 + klocal;
    }

    const int swz = (l & 7) << 4;
    const int qo  = (l >> 4) << 4;
    const int plF = (l & 15)*128 + (qo ^ (swz & 0x30)) + (swz & 0x40);

    f32x4 acc0[4][2], acc1[4][2];
    const f32x4 zz = {0.f, 0.f, 0.f, 0.f};
    #pragma unroll
    for (int a = 0; a < 4; ++a)
        #pragma unroll
        for (int b = 0; b < 2; ++b) { acc0[a][b] = zz; acc1[a][b] = zz; }

    for (int c = 0; c < 250; ++c) {
        int kid = c >> 1;
        int kd = kid/25, rr = kid - kd*25, kh = rr/5, kw = rr - kh*5;
        int koff = (kd*576 + kh*24 + kw)*128 + (c & 1)*64;

        __syncthreads();
        {
            const char* wsrc = (const char*)Wb + ((size_t)(m*250 + c))*32768 + w*8192;
            #pragma unroll
            for (int i = 0; i < 8; ++i)
                gload16(wsrc + i*1024 + l*16, lds + w*8192 + i*1024);
            #pragma unroll
            for (int i = 0; i < 4; ++i)
                gload16(preP[i] + koff, lds + 32768 + w*4096 + i*1024);
        }
        __syncthreads();

        #pragma unroll
        for (int ks = 0; ks < 2; ++ks) {
            const int kx = ks ? 64 : 0;
            h8 af[2][4], bf[2][2];
            #pragma unroll
            for (int v = 0; v < 2; ++v) {
                #pragma unroll
                for (int mf = 0; mf < 4; ++mf)
                    af[v][mf] = *(const h8*)(lds + v*16384 + (wm*64 + mf*16)*128 + (plF ^ kx));
                #pragma unroll
                for (int nf = 0; nf < 2; ++nf)
                    bf[v][nf] = *(const h8*)(lds + 32768 + v*8192 + (wn*32 + nf*16)*128 + (plF ^ kx));
            }
            #pragma unroll
            for (int mf = 0; mf < 4; ++mf)
                #pragma unroll
                for (int nf = 0; nf < 2; ++nf) {
                    acc0[mf][nf] = __builtin_amdgcn_mfma_f32_16x16x32_f16(af[0][mf], bf[0][nf], acc0[mf][nf], 0,0,0);
                    acc1[mf][nf] = __builtin_amdgcn_mfma_f32_16x16x32_f16(af[0][mf], bf[1][nf], acc1[mf][nf], 0,0,0);
                    acc1[mf][nf] = __builtin_amdgcn_mfma_f32_16x16x32_f16(af[1][mf], bf[0][nf], acc1[mf][nf], 0,0,0);
                }
        }
    }

    const float s1 = 4.8828125e-04f;
    #pragma unroll
    for (int mf = 0; mf < 4; ++mf)
        #pragma unroll
        for (int nf = 0; nf < 2; ++nf) {
            f32x4 r = acc0[mf][nf] + s1*acc1[mf][nf];
            int co = m*128 + wm*64 + mf*16 + ((l>>4)<<2);
            int n  = n0 + wn*32 + nf*16 + (l&15);
            size_t base = (size_t)n*256 + co;
            h4 v0, v1;
            #pragma unroll
            for (int rr = 0; rr < 4; ++rr) {
                float x = fmaxf(r[rr] + bias[co + rr], 0.f);
                _Float16 t0, t1; split2(x, t0, t1);
                v0[rr] = t0; v1[rr] = t1;
            }
            *(h4*)(h1cl + base)         = v0;
            *(h4*)(h1cl + H1_PL + base) = v1;
        }
}

// ---------------- conv2 MFMA, z-split partial slabs ----------------
__global__ __launch_bounds__(256, 3)
void k_conv2(const _Float16* __restrict__ h1cl, const char* __restrict__ Wb,
             float* __restrict__ h2p, int cBase, int NSt, int accum)
{
    extern __shared__ char lds[];
    const int tid = threadIdx.x;
    const int l   = tid & 63;
    const int w   = tid >> 6;
    const int wm  = w >> 1, wn = w & 1;
    const int n0  = blockIdx.x * 64;
    const int m   = blockIdx.y;
    const int per = (NSt + (int)gridDim.z - 1) / (int)gridDim.z;
    const int cl0 = blockIdx.z * per;
    const int cl1 = min(NSt, cl0 + per);

    const _Float16* preP[4];
    #pragma unroll
    for (int i = 0; i < 4; ++i) {
        int g   = w*4096 + i*1024 + l*16;
        int ver = g >> 13;
        int dd  = g & 8191;
        int nl  = dd >> 7;
        int lg  = (dd & 127) ^ ((nl & 7) << 4);
        int klocal = lg >> 1;
        int n = n0 + nl;
        int b2 = n >> 12, so = n & 4095;
        int x = so >> 8, y = (so >> 4) & 15, z = so & 15;
        preP[i] = h1cl + (size_t)ver*H1_PL
                       + ((size_t)(b2*8000 + x*400 + y*20 + z))*256 + klocal;
    }

    const int swz = (l & 7) << 4;
    const int qo  = (l >> 4) << 4;
    const int plF = (l & 15)*128 + (qo ^ (swz & 0x30)) + (swz & 0x40);

    f32x4 acc0[4][2], acc1[4][2];
    const f32x4 zz = {0.f, 0.f, 0.f, 0.f};
    #pragma unroll
    for (int a = 0; a < 4; ++a)
        #pragma unroll
        for (int b = 0; b < 2; ++b) { acc0[a][b] = zz; acc1[a][b] = zz; }

    for (int cl = cl0; cl < cl1; ++cl) {
        int cg = cBase + cl;
        int kid = cg >> 2;
        int kd = kid/25, rr = kid - kd*25, kh = rr/5, kw = rr - kh*5;
        int koff = (kd*400 + kh*20 + kw)*256 + (cg & 3)*64;

        __syncthreads();
        {
            const char* wsrc = (const char*)Wb + ((size_t)(m*NSt + cl))*32768 + w*8192;
            #pragma unroll
            for (int i = 0; i < 8; ++i)
                gload16(wsrc + i*1024 + l*16, lds + w*8192 + i*1024);
            #pragma unroll
            for (int i = 0; i < 4; ++i)
                gload16(preP[i] + koff, lds + 32768 + w*4096 + i*1024);
        }
        __syncthreads();

        #pragma unroll
        for (int ks = 0; ks < 2; ++ks) {
            const int kx = ks ? 64 : 0;
            h8 af[2][4], bf[2][2];
            #pragma unroll
            for (int v = 0; v < 2; ++v) {
                #pragma unroll
                for (int mf = 0; mf < 4; ++mf)
                    af[v][mf] = *(const h8*)(lds + v*16384 + (wm*64 + mf*16)*128 + (plF ^ kx));
                #pragma unroll
                for (int nf = 0; nf < 2; ++nf)
                    bf[v][nf] = *(const h8*)(lds + 32768 + v*8192 + (wn*32 + nf*16)*128 + (plF ^ kx));
            }
            #pragma unroll
            for (int mf = 0; mf < 4; ++mf)
                #pragma unroll
                for (int nf = 0; nf < 2; ++nf) {
                    acc0[mf][nf] = __builtin_amdgcn_mfma_f32_16x16x32_f16(af[0][mf], bf[0][nf], acc0[mf][nf], 0,0,0);
                    acc1[mf][nf] = __builtin_amdgcn_mfma_f32_16x16x32_f16(af[0][mf], bf[1][nf], acc1[mf][nf], 0,0,0);
                    acc1[mf][nf] = __builtin_amdgcn_mfma_f32_16x16x32_f16(af[1][mf], bf[0][nf], acc1[mf][nf], 0,0,0);
                }
        }
    }

    const float s1 = 4.8828125e-04f;
    float* oz = h2p + (size_t)blockIdx.z * 2097152;
    #pragma unroll
    for (int mf = 0; mf < 4; ++mf)
        #pragma unroll
        for (int nf = 0; nf < 2; ++nf) {
            f32x4 r = acc0[mf][nf] + s1*acc1[mf][nf];
            int co = m*128 + wm*64 + mf*16 + ((l>>4)<<2);
            int n  = n0 + wn*32 + nf*16 + (l&15);
            int b2 = n >> 12, so = n & 4095;
            #pragma unroll
            for (int rr = 0; rr < 4; ++rr) {
                size_t idx = ((size_t)(b2*256 + co + rr))*4096 + so;
                if (accum) oz[idx] += r[rr];
                else       oz[idx]  = r[rr];
            }
        }
}

// ---------------- h2 -> channel-last fp16x2 limbs (fused combine+bias+relu+transpose) ----------------
__global__ __launch_bounds__(256)
void k_h2cl(const float* __restrict__ p0, const float* __restrict__ bias,
            _Float16* __restrict__ h2cl)
{
    __shared__ float tile[32][33];
    int b2  = blockIdx.z;
    int so0 = blockIdx.x * 32;   // 128 tiles
    int co0 = blockIdx.y * 32;   // 8 tiles
    int i = threadIdx.x >> 5;    // 0..7
    int j = threadIdx.x & 31;
    #pragma unroll
    for (int r = 0; r < 32; r += 8) {
        size_t idx = ((size_t)(b2*256 + co0 + i + r))*4096 + so0 + j;
        float v = p0[idx] + p0[2097152 + idx] + p0[4194304 + idx] + bias[co0 + i + r];
        tile[i + r][j] = fmaxf(v, 0.f);
    }
    __syncthreads();
    #pragma unroll
    for (int r = 0; r < 32; r += 8) {
        float x = tile[j][i + r];
        _Float16 a0, a1; split2(x, a0, a1);
        size_t o = ((size_t)(b2*4096 + so0 + i + r))*256 + co0 + j;
        h2cl[o]           = a0;
        h2cl[o + H2CL_PL] = a1;
    }
}

// ---------------- prim MFMA GEMM (conv2 clone): 256->256, k9, s2, 16^3 -> 4^3 ----------------
// grid (2 nTile, 2 mTile, 64 z). Stage covers chunks [0, cps4); kid = kidBase + (cl>>2).
__global__ __launch_bounds__(256, 3)
void k_primm(const _Float16* __restrict__ h2cl, const char* __restrict__ Wb,
             float* __restrict__ pp, int kidBase, int cps4, int accum)
{
    extern __shared__ char lds[];
    const int tid = threadIdx.x;
    const int l   = tid & 63;
    const int w   = tid >> 6;
    const int wm  = w >> 1, wn = w & 1;
    const int n0  = blockIdx.x * 64;
    const int m   = blockIdx.y;
    const int per = (cps4 + 63) >> 6;
    const int cl0 = blockIdx.z * per;
    const int cl1 = min(cps4, cl0 + per);

    const _Float16* preP[4];
    #pragma unroll
    for (int i = 0; i < 4; ++i) {
        int g   = w*4096 + i*1024 + l*16;
        int ver = g >> 13;
        int dd  = g & 8191;
        int nl  = dd >> 7;
        int lg  = (dd & 127) ^ ((nl & 7) << 4);
        int klocal = lg >> 1;
        int n = n0 + nl;
        int b2 = n >> 6, so = n & 63;
        int x = so >> 4, y = (so >> 2) & 3, z = so & 3;
        preP[i] = h2cl + (size_t)ver*H2CL_PL
                       + ((size_t)(b2*4096 + x*512 + y*32 + z*2))*256 + klocal;
    }

    const int swz = (l & 7) << 4;
    const int qo  = (l >> 4) << 4;
    const int plF = (l & 15)*128 + (qo ^ (swz & 0x30)) + (swz & 0x40);

    f32x4 acc0[4][2], acc1[4][2];
    const f32x4 zz = {0.f, 0.f, 0.f, 0.f};
    #pragma unroll
    for (int a = 0; a < 4; ++a)
        #pragma unroll
        for (int b = 0; b < 2; ++b) { acc0[a][b] = zz; acc1[a][b] = zz; }

    for (int cl = cl0; cl < cl1; ++cl) {
        int kid = kidBase + (cl >> 2);
        int kd = kid/81, rr = kid - kd*81, kh = rr/9, kw = rr - kh*9;
        int koff = (kd*256 + kh*16 + kw)*256 + (cl & 3)*64;

        __syncthreads();
        {
            const char* wsrc = (const char*)Wb + ((size_t)(m*cps4 + cl))*32768 + w*8192;
            #pragma unroll
            for (int i = 0; i < 8; ++i)
                gload16(wsrc + i*1024 + l*16, lds + w*8192 + i*1024);
            #pragma unroll
            for (int i = 0; i < 4; ++i)
                gload16(preP[i] + koff, lds + 32768 + w*4096 + i*1024);
        }
        __syncthreads();

        #pragma unroll
        for (int ks = 0; ks < 2; ++ks) {
            const int kx = ks ? 64 : 0;
            h8 af[2][4], bf[2][2];
            #pragma unroll
            for (int v = 0; v < 2; ++v) {
                #pragma unroll
                for (int mf = 0; mf < 4; ++mf)
                    af[v][mf] = *(const h8*)(lds + v*16384 + (wm*64 + mf*16)*128 + (plF ^ kx));
                #pragma unroll
                for (int nf = 0; nf < 2; ++nf)
                    bf[v][nf] = *(const h8*)(lds + 32768 + v*8192 + (wn*32 + nf*16)*128 + (plF ^ kx));
            }
            #pragma unroll
            for (int mf = 0; mf < 4; ++mf)
                #pragma unroll
                for (int nf = 0; nf < 2; ++nf) {
                    acc0[mf][nf] = __builtin_amdgcn_mfma_f32_16x16x32_f16(af[0][mf], bf[0][nf], acc0[mf][nf], 0,0,0);
                    acc1[mf][nf] = __builtin_amdgcn_mfma_f32_16x16x32_f16(af[0][mf], bf[1][nf], acc1[mf][nf], 0,0,0);
                    acc1[mf][nf] = __builtin_amdgcn_mfma_f32_16x16x32_f16(af[1][mf], bf[0][nf], acc1[mf][nf], 0,0,0);
                }
        }
    }

    const float s1 = 4.8828125e-04f;
    float* oz = pp + (size_t)blockIdx.z * 32768;
    #pragma unroll
    for (int mf = 0; mf < 4; ++mf)
        #pragma unroll
        for (int nf = 0; nf < 2; ++nf) {
            f32x4 r = acc0[mf][nf] + s1*acc1[mf][nf];
            int co = m*128 + wm*64 + mf*16 + ((l>>4)<<2);
            int n  = n0 + wn*32 + nf*16 + (l&15);
            int b2 = n >> 6, so = n & 63;
            #pragma unroll
            for (int rr = 0; rr < 4; ++rr) {
                size_t idx = ((size_t)(b2*256 + co + rr))*64 + so;
                if (accum) oz[idx] += r[rr];
                else       oz[idx]  = r[rr];
            }
        }
}

// ---------------- prim reduce stage 1: 64 slabs -> 8 partial slabs ----------------
__global__ __launch_bounds__(256)
void k_pr1(const float* __restrict__ pp, float* __restrict__ out1)
{
    int e = blockIdx.x*256 + threadIdx.x;   // 32768 elements, grid.x = 128
    int y = blockIdx.y;                      // 8 groups of 8 slabs
    const float* src = pp + (size_t)y*8*32768 + e;
    float a = 0.f;
    #pragma unroll
    for (int j = 0; j < 8; ++j) a += src[(size_t)j*32768];
    out1[y*32768 + e] = a;
}

// ---------------- prim reduce stage 2: 8 partials + bias + squash -> u ----------------
__global__ __launch_bounds__(256)
void k_pr2(const float* __restrict__ out1, const float* __restrict__ pbias,
           float* __restrict__ u)
{
    int g = blockIdx.x*256 + threadIdx.x;      // B*2048 = 4096
    int b = g >> 11;
    int i = g & 2047;
    int cap = i >> 6;
    int s   = i & 63;
    float vals[8];
    float sq = 0.f;
    #pragma unroll
    for (int c = 0; c < 8; ++c) {
        size_t base = ((size_t)(b*256) + cap*8 + c)*64 + s;
        float a = 0.f;
        #pragma unroll
        for (int j = 0; j < 8; ++j) a += out1[(size_t)j*32768 + base];
        float x = a + pbias[cap*8 + c];
        vals[c] = x;
        sq += x*x;
    }
    float scale = (sq / (1.f + sq)) / sqrtf(sq + 1e-8f);
    #pragma unroll
    for (int c = 0; c < 8; ++c) u[(size_t)g*8 + c] = vals[c]*scale;
}

// ---------------- routing ----------------
__global__ __launch_bounds__(256)
void k_route(const float* __restrict__ Wr, const float* __restrict__ u,
             float* __restrict__ s_buf)
{
    int j  = blockIdx.x;
    int i0 = blockIdx.y * 512;
    __shared__ float us[2*512*8];
    for (int idx = threadIdx.x; idx < 8192; idx += 256) {
        int b = idx >> 12;
        us[idx] = u[(size_t)b*16384 + (size_t)i0*8 + (idx & 4095)];
    }
    __syncthreads();
    int tid = threadIdx.x;
    int cc  = tid & 7;
    const float* Wj = Wr + (size_t)j*2048*512 + (size_t)i0*512;
    float a00 = 0.f, a01 = 0.f, a10 = 0.f, a11 = 0.f;
    for (int i = 0; i < 512; ++i) {
        float w0 = Wj[(size_t)i*512 + tid];
        float w1 = Wj[(size_t)i*512 + tid + 256];
        float u0 = us[i*8 + cc];
        float u1 = us[4096 + i*8 + cc];
        a00 += w0*u0; a01 += w1*u0; a10 += w0*u1; a11 += w1*u1;
    }
    __syncthreads();
    float* red = us;
    red[tid] = a00; red[256 + tid] = a01; red[512 + tid] = a10; red[768 + tid] = a11;
    __syncthreads();
    if (tid < 128) {
        int b = tid >> 6, d = tid & 63;
        const float* rb = red + b*512 + (d >> 5)*256 + (d & 31)*8;
        float s = 0.f;
        #pragma unroll
        for (int c2 = 0; c2 < 8; ++c2) s += rb[c2];
        atomicAdd(&s_buf[((size_t)b*50 + j)*64 + d], s * (1.0f/50.0f));
    }
}

// ---------------- squash v ----------------
__global__ __launch_bounds__(64)
void k_squash_v(const float* __restrict__ s_buf, float* __restrict__ v_buf)
{
    int row = blockIdx.x;
    int d   = threadIdx.x;
    float s  = s_buf[row*64 + d];
    float sq = s*s;
    #pragma unroll
    for (int o = 32; o > 0; o >>= 1) sq += __shfl_xor(sq, o);
    float scale = (sq / (1.f + sq)) / sqrtf(sq + 1e-8f);
    v_buf[row*64 + d] = s*scale;
}

// ---------------- dec1 -> fp16x2 channel-last limbs ----------------
__global__ __launch_bounds__(256)
void k_dec1(const float* __restrict__ v, const float* __restrict__ W,
            const float* __restrict__ bias, _Float16* __restrict__ d1cl)
{
    int g  = blockIdx.x*256 + threadIdx.x;  // 442368
    int co = g & 127;
    int t  = g >> 7;
    int o  = t % 1728;
    int b  = t / 1728;
    int ox = o / 144, oy = (o/12) % 12, oz = o % 12;
    int ix = ox/3, ka = ox - 3*ix;
    int iy = oy/3, kb = oy - 3*iy;
    int iz = oz/3, kc = oz - 3*iz;
    int widx = ka*9 + kb*3 + kc;
    int sidx = ix*16 + iy*4 + iz;
    float s = 0.f;
    for (int ci = 0; ci < 50; ++ci)
        s += v[((size_t)b*50 + ci)*64 + sidx] * W[((size_t)ci*128 + co)*27 + widx];
    float x = fmaxf(s + bias[co], 0.f);
    _Float16 a0, a1; split2(x, a0, a1);
    size_t base = (size_t)(b*1728 + o)*128 + co;
    d1cl[base]         = a0;
    d1cl[base + D1_PL] = a1;
}

// ---------------- dec2 MFMA, PARITY-DECOMPOSED (4-wave), per co-half ----------------
__global__ __launch_bounds__(256, 3)
void k_dec2p(const _Float16* __restrict__ d1cl, const char* __restrict__ Wb,
             const float* __restrict__ bias, float* __restrict__ out, int coBase)
{
    extern __shared__ char lds[];           // A 32KB + B 16KB
    const int tid = threadIdx.x;
    const int l   = tid & 63;
    const int w   = tid >> 6;
    const int wm  = w >> 1, wn = w & 1;
    const int cls = blockIdx.z;
    const int px  = (cls >> 2) & 1, py = (cls >> 1) & 1, pz = cls & 1;
    const int n0  = blockIdx.x * 64;        // class-local n over 3456
    const int m   = blockIdx.y;
    const int mG  = (coBase >> 7) + m;

    int cb = 0;
    for (int c = 0; c < cls; ++c) cb += 2 << __popc(c);
    const int nch = 2 << __popc(cls);

    const int nRow = tid & 63;
    const int q    = tid >> 6;
    const int nT   = n0 + nRow;
    const int b2s  = nT / 1728;
    const int rs   = nT - b2s*1728;
    const int oxh  = rs/144, oyh = (rs/12)%12, ozh = rs%12;
    const int posB = b2s*1728;
    const int bw0 = 32768 + nRow*128 + ((q*32)      ^ ((nRow&7)<<4));
    const int bw1 = 32768 + nRow*128 + ((q*32 + 16) ^ ((nRow&7)<<4));

    const int swz = (l & 7) << 4;
    const int qo  = (l >> 4) << 4;
    const int plF = (l & 15)*128 + (qo ^ (swz & 0x30)) + (swz & 0x40);

    f32x4 acc0[4][2], acc1[4][2];
    const f32x4 zz = {0.f, 0.f, 0.f, 0.f};
    #pragma unroll
    for (int a = 0; a < 4; ++a)
        #pragma unroll
        for (int b = 0; b < 2; ++b) { acc0[a][b] = zz; acc1[a][b] = zz; }

    const h8 z8 = {};
    for (int c = 0; c < nch; ++c) {
        int ti = c >> 1, ch = c & 1;
        int kd, kh, kw;
        tapDecode(cls, ti, kd, kh, kw);
        int txh = oxh + (px && kd == 0);
        int tyh = oyh + (py && kh == 0);
        int tzh = ozh + (pz && kw == 0);
        bool ok = (txh < 12) && (tyh < 12) && (tzh < 12);
        const _Float16* src = d1cl + (size_t)(posB + txh*144 + tyh*12 + tzh)*128
                                   + ch*64 + q*16;
        h8 b0a = *(const h8*)(src);
        h8 b0b = *(const h8*)(src + 8);
        h8 b1a = *(const h8*)(src + D1_PL);
        h8 b1b = *(const h8*)(src + D1_PL + 8);

        __syncthreads();
        {
            const char* wsrc = (const char*)Wb + ((size_t)(mG*54 + cb + c))*32768 + w*8192;
            #pragma unroll
            for (int i = 0; i < 8; ++i)
                gload16(wsrc + i*1024 + l*16, lds + w*8192 + i*1024);
        }
        *(h8*)(lds + bw0)         = ok ? b0a : z8;
        *(h8*)(lds + bw1)         = ok ? b0b : z8;
        *(h8*)(lds + 8192 + bw0)  = ok ? b1a : z8;
        *(h8*)(lds + 8192 + bw1)  = ok ? b1b : z8;
        __syncthreads();

        #pragma unroll
        for (int ks = 0; ks < 2; ++ks) {
            const int kx = ks ? 64 : 0;
            h8 af[2][4], bf[2][2];
            #pragma unroll
            for (int v = 0; v < 2; ++v) {
                #pragma unroll
                for (int mf = 0; mf < 4; ++mf)
                    af[v][mf] = *(const h8*)(lds + v*16384 + (wm*64 + mf*16)*128 + (plF ^ kx));
                #pragma unroll
                for (int nf = 0; nf < 2; ++nf)
                    bf[v][nf] = *(const h8*)(lds + 32768 + v*8192 + (wn*32 + nf*16)*128 + (plF ^ kx));
            }
            #pragma unroll
            for (int mf = 0; mf < 4; ++mf)
                #pragma unroll
                for (int nf = 0; nf < 2; ++nf) {
                    acc0[mf][nf] = __builtin_amdgcn_mfma_f32_16x16x32_f16(af[0][mf], bf[0][nf], acc0[mf][nf], 0,0,0);
                    acc1[mf][nf] = __builtin_amdgcn_mfma_f32_16x16x32_f16(af[0][mf], bf[1][nf], acc1[mf][nf], 0,0,0);
                    acc1[mf][nf] = __builtin_amdgcn_mfma_f32_16x16x32_f16(af[1][mf], bf[0][nf], acc1[mf][nf], 0,0,0);
                }
        }
    }

    const float s1 = 4.8828125e-04f;
    #pragma unroll
    for (int mf = 0; mf < 4; ++mf)
        #pragma unroll
        for (int nf = 0; nf < 2; ++nf) {
            f32x4 r = acc0[mf][nf] + s1*acc1[mf][nf];
            int coL = m*128 + wm*64 + mf*16 + ((l>>4)<<2);
            int coG = coBase + coL;
            int nT2 = n0 + wn*32 + nf*16 + (l&15);
            int b2  = nT2 / 1728;
            int r2  = nT2 - b2*1728;
            int ax  = r2/144, ay = (r2/12)%12, az = r2%12;
            int outIdx = b2*13824 + (2*ax + px)*576 + (2*ay + py)*24 + (2*az + pz);
            float4 v;
            v.x = fmaxf(r[0] + bias[coG + 0], 0.f);
            v.y = fmaxf(r[1] + bias[coG + 1], 0.f);
            v.z = fmaxf(r[2] + bias[coG + 2], 0.f);
            v.w = fmaxf(r[3] + bias[coG + 3], 0.f);
            *(float4*)(out + (size_t)outIdx*256 + coL) = v;
        }
}

// ---------------- final gather (per co-half) ----------------
__global__ __launch_bounds__(256)
void k_gather(const float* __restrict__ d2h, const int* __restrict__ vid,
              float* __restrict__ out, int colOff)
{
    int g  = blockIdx.x*256 + threadIdx.x;   // B*P*64 float4 units
    int qq = g & 63;
    int bp = g >> 6;
    int v  = vid[bp];
    int b  = bp >> 13;
    float4 val = *(const float4*)&d2h[((size_t)(b*N3 + v))*256 + qq*4];
    *(float4*)&out[(size_t)bp*512 + colOff + qq*4] = val;
}

extern "C" void kernel_launch(void* const* d_in, const int* in_sizes, int n_in,
                              void* d_out, int out_size, void* d_ws, size_t ws_size,
                              hipStream_t stream)
{
    (void)in_sizes; (void)n_in; (void)out_size; (void)ws_size;
    const float* pcl  = (const float*)d_in[0];
    const float* feat = (const float*)d_in[1];
    const float* c1w  = (const float*)d_in[3];
    const float* c1b  = (const float*)d_in[4];
    const float* c2w  = (const float*)d_in[5];
    const float* c2b  = (const float*)d_in[6];
    const float* pw   = (const float*)d_in[7];
    const float* pb   = (const float*)d_in[8];
    const float* rw   = (const float*)d_in[9];
    const float* d1w  = (const float*)d_in[10];
    const float* d1b_ = (const float*)d_in[11];
    const float* d2w  = (const float*)d_in[12];
    const float* d2b  = (const float*)d_in[13];

    char* ws = (char*)d_ws;
    float*     meshS  = (float*)(ws + MESHS_OFF);
    _Float16*  m16    = (_Float16*)(ws + M16_OFF);
    _Float16*  h1cl   = (_Float16*)(ws + H1CL_OFF);
    char*      Wb     = ws + WB_OFF;
    char*      Wb2c   = ws + WB2C_OFF;
    float*     h2p    = (float*)(ws + H2P_OFF);
    char*      img    = ws + IMG_OFF;
    _Float16*  h2cl   = (_Float16*)(ws + H2CL_OFF);
    float*     p_part = (float*)(ws + PPART_OFF);
    float*     pr1    = (float*)(ws + PR1_OFF);
    char*      Wbd    = ws + WBD_OFF;
    float*     d2h    = (float*)(ws + D2H_OFF);
    _Float16*  d1cl   = (_Float16*)(ws + D1CL_OFF);
    int*       vid    = (int*)(ws + VID_OFF);
    float*     u_buf  = (float*)(ws + UBUF_OFF);
    float*     s_buf  = (float*)(ws + SBUF_OFF);
    float*     v_buf  = (float*)(ws + VBUF_OFF);

    k_vid<<<dim3(B_), dim3(256), 0, stream>>>(pcl, vid);

    hipMemsetAsync(meshS, 0, 14155776, stream);
    k_scatter<<<dim3(8192), dim3(256), 0, stream>>>(feat, vid, meshS);
    k_meshsplit<<<dim3(3456), dim3(256), 0, stream>>>(meshS, m16);

    // conv1
    k_splitw1<<<dim3(16000), dim3(256), 0, stream>>>(c1w, Wb);
    k_conv1<<<dim3(250, 2), dim3(256), 49152, stream>>>(m16, Wb, c1b, h1cl);

    // conv2: two half-K weight stages, each z=3 split-K -> 3 partial slabs
    k_splitw2<<<dim3(15872), dim3(256), 0, stream>>>(c2w, Wb2c, 0, 248);
    k_conv2<<<dim3(128, 2, 3), dim3(256), 49152, stream>>>(h1cl, Wb2c, h2p, 0, 248, 0);
    k_splitw2<<<dim3(16128), dim3(256), 0, stream>>>(c2w, Wb2c, 248, 252);
    k_conv2<<<dim3(128, 2, 3), dim3(256), 49152, stream>>>(h1cl, Wb2c, h2p, 248, 252, 1);

    // h2 -> channel-last limbs (fused combine+bias+relu+transpose+split)
    k_h2cl<<<dim3(128, 8, 2), dim3(256), 0, stream>>>(h2p, c2b, h2cl);

    // primary caps: MFMA GEMM over 5 weight-image stages (K = 729 kids x 256 ci)
    {
        const int bases[5] = {0, 146, 292, 438, 584};
        const int kidsA[5] = {146, 146, 146, 146, 145};
        for (int s = 0; s < 5; ++s) {
            int kids = kidsA[s];
            int cps4 = kids * 4;
            k_wimg<<<dim3((kids + 15)/16, 128, 2), dim3(256), 0, stream>>>(
                pw, img, bases[s], kids, cps4);
            k_primm<<<dim3(2, 2, 64), dim3(256), 49152, stream>>>(
                h2cl, img, p_part, bases[s], cps4, s > 0);
        }
    }
    k_pr1<<<dim3(128, 8), dim3(256), 0, stream>>>(p_part, pr1);
    k_pr2<<<dim3(16), dim3(256), 0, stream>>>(pr1, pb, u_buf);

    hipMemsetAsync(s_buf, 0, 25600, stream);
    k_route<<<dim3(50, 4), dim3(256), 0, stream>>>(rw, u_buf, s_buf);
    k_squash_v<<<dim3(100), dim3(64), 0, stream>>>(s_buf, v_buf);

    k_dec1<<<dim3(1728), dim3(256), 0, stream>>>(v_buf, d1w, d1b_, d1cl);

    // dec2 weights, parity-grouped (Wbd overlaps img region, dead by then)
    k_splitwd2p<<<dim3(6912), dim3(256), 0, stream>>>(d2w, Wbd);

    k_dec2p<<<dim3(54, 2, 8), dim3(256), 49152, stream>>>(d1cl, Wbd, d2b, d2h, 0);
    k_gather<<<dim3(4096), dim3(256), 0, stream>>>(d2h, vid, (float*)d_out, 0);
    k_dec2p<<<dim3(54, 2, 8), dim3(256), 49152, stream>>>(d1cl, Wbd, d2b, d2h, 256);
    k_gather<<<dim3(4096), dim3(256), 0, stream>>>(d2h, vid, (float*)d_out, 256);
}

// Round 17
// 1343.219 us; speedup vs baseline: 1.2517x; 1.2517x over previous
//
#include <hip/hip_runtime.h>
#include <cstdint>
#include <cstddef>

typedef _Float16 h8 __attribute__((ext_vector_type(8)));
typedef _Float16 h4 __attribute__((ext_vector_type(4)));
typedef float    f32x4 __attribute__((ext_vector_type(4)));

#define B_   2
#define P_   8192
#define NVOX 24
#define N3   13824

// ---- workspace layout (bytes). Peak 61.2 MB < 63.9 MB proven bound. ----
#define MESHS_OFF 0ull
#define M16_OFF   14155776ull
#define H1CL_OFF  28311552ull
#define WB_OFF    44695552ull
#define WB2C_OFF  44695552ull
#define H2P_OFF   0ull
#define PPART_OFF 25165824ull
#define PR1_OFF   53477376ull
#define WBD_OFF   0ull
#define D2H_OFF   10616832ull
#define D1CL_OFF  38928384ull
#define VID_OFF   63504384ull
#define UBUF_OFF  63700992ull
#define SBUF_OFF  63832064ull
#define VBUF_OFF  63857664ull

#define M16_PL   3538944ull     // mesh16 plane stride (elements)
#define H1_PL    4096000ull     // h1cl plane stride (elements)
#define D1_PL    442368ull      // d1cl plane stride (elements)

// ---------------- helpers ----------------
__device__ inline void split2(float x, _Float16& a0, _Float16& a1)
{
    a0 = (_Float16)x;
    float r = x - (float)a0;
    a1 = (_Float16)(r * 2048.0f);
}

__device__ inline void gload16(const void* g, void* l)
{
    __builtin_amdgcn_global_load_lds(
        (const __attribute__((address_space(1))) char*)g,
        (__attribute__((address_space(3))) char*)l, 16, 0, 0);
}

// parity-class helpers for dec2
__device__ inline void tapDecode(int cls, int ti, int& kd, int& kh, int& kw)
{
    int px = (cls >> 2) & 1, py = (cls >> 1) & 1, pz = cls & 1;
    int tiz = pz ? (ti & 1) : 0;
    int t1  = ti >> pz;
    int tiy = py ? (t1 & 1) : 0;
    int tix = t1 >> py;
    kd = px ? tix*2 : 1;
    kh = py ? tiy*2 : 1;
    kw = pz ? tiz*2 : 1;
}

// ---------------- voxel ids ----------------
__global__ __launch_bounds__(256)
void k_vid(const float* __restrict__ pcl, int* __restrict__ vid)
{
    int b = blockIdx.x;
    const float* pb = pcl + (size_t)b * P_ * 3;
    float mn[3] = {3e38f, 3e38f, 3e38f};
    float mx[3] = {-3e38f, -3e38f, -3e38f};
    for (int p = threadIdx.x; p < P_; p += 256) {
        #pragma unroll
        for (int d = 0; d < 3; ++d) {
            float v = pb[p*3 + d];
            mn[d] = fminf(mn[d], v);
            mx[d] = fmaxf(mx[d], v);
        }
    }
    __shared__ float red[6][256];
    #pragma unroll
    for (int d = 0; d < 3; ++d) { red[d][threadIdx.x] = mn[d]; red[3+d][threadIdx.x] = mx[d]; }
    __syncthreads();
    for (int s = 128; s > 0; s >>= 1) {
        if (threadIdx.x < (unsigned)s) {
            #pragma unroll
            for (int d = 0; d < 3; ++d) {
                red[d][threadIdx.x]   = fminf(red[d][threadIdx.x],   red[d][threadIdx.x + s]);
                red[3+d][threadIdx.x] = fmaxf(red[3+d][threadIdx.x], red[3+d][threadIdx.x + s]);
            }
        }
        __syncthreads();
    }
    float mn0 = red[0][0], mn1 = red[1][0], mn2 = red[2][0];
    float dd0 = red[3][0] - mn0 + 1e-9f;
    float dd1 = red[4][0] - mn1 + 1e-9f;
    float dd2 = red[5][0] - mn2 + 1e-9f;
    for (int p = threadIdx.x; p < P_; p += 256) {
        float fx = (pb[p*3+0] - mn0) / dd0 * 24.0f;
        float fy = (pb[p*3+1] - mn1) / dd1 * 24.0f;
        float fz = (pb[p*3+2] - mn2) / dd2 * 24.0f;
        int ix = (int)floorf(fx); ix = ix < 0 ? 0 : (ix > 23 ? 23 : ix);
        int iy = (int)floorf(fy); iy = iy < 0 ? 0 : (iy > 23 ? 23 : iy);
        int iz = (int)floorf(fz); iz = iz < 0 ? 0 : (iz > 23 ? 23 : iz);
        vid[b*P_ + p] = ix*576 + iy*24 + iz;
    }
}

// ---------------- scatter-add point features -> meshS (B, N3, 128) ----------------
__global__ __launch_bounds__(256)
void k_scatter(const float* __restrict__ feat, const int* __restrict__ vid,
               float* __restrict__ meshS)
{
    int g = blockIdx.x*256 + threadIdx.x;      // B*P*C = 2,097,152
    int c  = g & 127;
    int bp = g >> 7;
    int v  = vid[bp];
    int b  = bp >> 13;
    atomicAdd(&meshS[((size_t)b*N3 + v)*128 + c], feat[g]);
}

// ---------------- mesh fp32 -> fp16x2 limb planes ----------------
__global__ __launch_bounds__(256)
void k_meshsplit(const float* __restrict__ meshS, _Float16* __restrict__ m16)
{
    int g = blockIdx.x*256 + threadIdx.x;   // 884,736 float4 groups
    int e = g*4;
    float4 a = *(const float4*)(meshS + e);
    h4 v0, v1;
    float xs[4] = {a.x, a.y, a.z, a.w};
    #pragma unroll
    for (int j = 0; j < 4; ++j) {
        _Float16 t0, t1; split2(xs[j], t0, t1);
        v0[j] = t0; v1[j] = t1;
    }
    *(h4*)(m16 + e)          = v0;
    *(h4*)(m16 + M16_PL + e) = v1;
}

// ---------------- pre-split conv1 weights ----------------
__global__ __launch_bounds__(256)
void k_splitw1(const float* __restrict__ W, char* __restrict__ Wb)
{
    int g = blockIdx.x*256 + threadIdx.x;   // 4,096,000
    int el   = g & 8191;
    int tile = g >> 13;                      // m*250 + c
    int m = tile / 250, c = tile - m*250;
    int co = el >> 6, kl = el & 63;
    int kg = c*64 + kl;
    int kid = kg >> 7, ci = kg & 127;
    float x = W[((size_t)((m*128 + co)*128 + ci))*125 + kid];
    _Float16 a0, a1; split2(x, a0, a1);
    char* dst = Wb + (size_t)tile*32768 + (co*128 + ((kl*2) ^ ((co&7)<<4)));
    *(_Float16*)(dst)         = a0;
    *(_Float16*)(dst + 16384) = a1;
}

// ---------------- pre-split conv2 weights (half-K at a time) ----------------
__global__ __launch_bounds__(256)
void k_splitw2(const float* __restrict__ W, char* __restrict__ Wb, int cBase, int NC)
{
    int g = blockIdx.x*256 + threadIdx.x;   // 2*NC*8192
    int el   = g & 8191;
    int tile = g >> 13;                      // m*NC + cl
    int m = tile / NC, cl = tile - m*NC;
    int c = cBase + cl;
    int co = el >> 6, kl = el & 63;
    int kg = c*64 + kl;
    int kid = kg >> 8, ci = kg & 255;
    float x = W[((size_t)((m*128 + co)*256 + ci))*125 + kid];
    _Float16 a0, a1; split2(x, a0, a1);
    char* dst = Wb + (size_t)tile*32768 + (co*128 + ((kl*2) ^ ((co&7)<<4)));
    *(_Float16*)(dst)         = a0;
    *(_Float16*)(dst + 16384) = a1;
}

// ---------------- pre-split dec2 weights, PARITY-GROUPED ----------------
__global__ __launch_bounds__(256)
void k_splitwd2p(const float* __restrict__ W, char* __restrict__ Wb)
{
    int g = blockIdx.x*256 + threadIdx.x;   // 216*8192 = 1,769,472
    int el   = g & 8191;
    int tile = g >> 13;                      // mG*54 + chunkG
    int mG = tile / 54, chunkG = tile - mG*54;
    int co = el >> 6, kl = el & 63;
    int rem = chunkG, cls = 0;
    for (int c = 0; c < 8; ++c) {
        int cc = 2 << __popc(c);
        if (rem < cc) { cls = c; break; }
        rem -= cc;
    }
    int k  = rem*64 + kl;
    int ti = k >> 7;
    int ci = k & 127;
    int kd, kh, kw;
    tapDecode(cls, ti, kd, kh, kw);
    int kid = kd*9 + kh*3 + kw;
    float x = W[((size_t)ci*512 + (mG*128 + co))*27 + kid];
    _Float16 a0, a1; split2(x, a0, a1);
    char* dst = Wb + (size_t)tile*32768 + (co*128 + ((kl*2) ^ ((co&7)<<4)));
    *(_Float16*)(dst)         = a0;
    *(_Float16*)(dst + 16384) = a1;
}

// ---------------- conv1 MFMA (proven r12 structure) ----------------
__global__ __launch_bounds__(256, 3)
void k_conv1(const _Float16* __restrict__ m16, const char* __restrict__ Wb,
             const float* __restrict__ bias, _Float16* __restrict__ h1cl)
{
    extern __shared__ char lds[];           // A 32KB + B 16KB = 48KB
    const int tid = threadIdx.x;
    const int l   = tid & 63;
    const int w   = tid >> 6;
    const int wm  = w >> 1, wn = w & 1;
    const int n0  = blockIdx.x * 64;
    const int m   = blockIdx.y;

    const _Float16* preP[4];
    #pragma unroll
    for (int i = 0; i < 4; ++i) {
        int g   = w*4096 + i*1024 + l*16;
        int ver = g >> 13;
        int dd  = g & 8191;
        int nl  = dd >> 7;
        int lg  = (dd & 127) ^ ((nl & 7) << 4);
        int klocal = lg >> 1;
        int n  = n0 + nl;
        int b2 = n / 8000;
        int so = n - b2*8000;
        int x = so/400, y = (so/20)%20, z = so%20;
        preP[i] = m16 + (size_t)ver*M16_PL
                      + ((size_t)(b2*13824 + x*576 + y*24 + z))*128 + klocal;
    }

    const int swz = (l & 7) << 4;
    const int qo  = (l >> 4) << 4;
    const int plF = (l & 15)*128 + (qo ^ (swz & 0x30)) + (swz & 0x40);

    f32x4 acc0[4][2], acc1[4][2];
    const f32x4 zz = {0.f, 0.f, 0.f, 0.f};
    #pragma unroll
    for (int a = 0; a < 4; ++a)
        #pragma unroll
        for (int b = 0; b < 2; ++b) { acc0[a][b] = zz; acc1[a][b] = zz; }

    for (int c = 0; c < 250; ++c) {
        int kid = c >> 1;
        int kd = kid/25, rr = kid - kd*25, kh = rr/5, kw = rr - kh*5;
        int koff = (kd*576 + kh*24 + kw)*128 + (c & 1)*64;

        __syncthreads();
        {
            const char* wsrc = (const char*)Wb + ((size_t)(m*250 + c))*32768 + w*8192;
            #pragma unroll
            for (int i = 0; i < 8; ++i)
                gload16(wsrc + i*1024 + l*16, lds + w*8192 + i*1024);
            #pragma unroll
            for (int i = 0; i < 4; ++i)
                gload16(preP[i] + koff, lds + 32768 + w*4096 + i*1024);
        }
        __syncthreads();

        #pragma unroll
        for (int ks = 0; ks < 2; ++ks) {
            const int kx = ks ? 64 : 0;
            h8 af[2][4], bf[2][2];
            #pragma unroll
            for (int v = 0; v < 2; ++v) {
                #pragma unroll
                for (int mf = 0; mf < 4; ++mf)
                    af[v][mf] = *(const h8*)(lds + v*16384 + (wm*64 + mf*16)*128 + (plF ^ kx));
                #pragma unroll
                for (int nf = 0; nf < 2; ++nf)
                    bf[v][nf] = *(const h8*)(lds + 32768 + v*8192 + (wn*32 + nf*16)*128 + (plF ^ kx));
            }
            #pragma unroll
            for (int mf = 0; mf < 4; ++mf)
                #pragma unroll
                for (int nf = 0; nf < 2; ++nf) {
                    acc0[mf][nf] = __builtin_amdgcn_mfma_f32_16x16x32_f16(af[0][mf], bf[0][nf], acc0[mf][nf], 0,0,0);
                    acc1[mf][nf] = __builtin_amdgcn_mfma_f32_16x16x32_f16(af[0][mf], bf[1][nf], acc1[mf][nf], 0,0,0);
                    acc1[mf][nf] = __builtin_amdgcn_mfma_f32_16x16x32_f16(af[1][mf], bf[0][nf], acc1[mf][nf], 0,0,0);
                }
        }
    }

    const float s1 = 4.8828125e-04f;
    #pragma unroll
    for (int mf = 0; mf < 4; ++mf)
        #pragma unroll
        for (int nf = 0; nf < 2; ++nf) {
            f32x4 r = acc0[mf][nf] + s1*acc1[mf][nf];
            int co = m*128 + wm*64 + mf*16 + ((l>>4)<<2);
            int n  = n0 + wn*32 + nf*16 + (l&15);
            size_t base = (size_t)n*256 + co;
            h4 v0, v1;
            #pragma unroll
            for (int rr = 0; rr < 4; ++rr) {
                float x = fmaxf(r[rr] + bias[co + rr], 0.f);
                _Float16 t0, t1; split2(x, t0, t1);
                v0[rr] = t0; v1[rr] = t1;
            }
            *(h4*)(h1cl + base)         = v0;
            *(h4*)(h1cl + H1_PL + base) = v1;
        }
}

// ---------------- conv2 MFMA, z-split partial slabs ----------------
__global__ __launch_bounds__(256, 3)
void k_conv2(const _Float16* __restrict__ h1cl, const char* __restrict__ Wb,
             float* __restrict__ h2p, int cBase, int NSt, int accum)
{
    extern __shared__ char lds[];
    const int tid = threadIdx.x;
    const int l   = tid & 63;
    const int w   = tid >> 6;
    const int wm  = w >> 1, wn = w & 1;
    const int n0  = blockIdx.x * 64;
    const int m   = blockIdx.y;
    const int per = (NSt + (int)gridDim.z - 1) / (int)gridDim.z;
    const int cl0 = blockIdx.z * per;
    const int cl1 = min(NSt, cl0 + per);

    const _Float16* preP[4];
    #pragma unroll
    for (int i = 0; i < 4; ++i) {
        int g   = w*4096 + i*1024 + l*16;
        int ver = g >> 13;
        int dd  = g & 8191;
        int nl  = dd >> 7;
        int lg  = (dd & 127) ^ ((nl & 7) << 4);
        int klocal = lg >> 1;
        int n = n0 + nl;
        int b2 = n >> 12, so = n & 4095;
        int x = so >> 8, y = (so >> 4) & 15, z = so & 15;
        preP[i] = h1cl + (size_t)ver*H1_PL
                       + ((size_t)(b2*8000 + x*400 + y*20 + z))*256 + klocal;
    }

    const int swz = (l & 7) << 4;
    const int qo  = (l >> 4) << 4;
    const int plF = (l & 15)*128 + (qo ^ (swz & 0x30)) + (swz & 0x40);

    f32x4 acc0[4][2], acc1[4][2];
    const f32x4 zz = {0.f, 0.f, 0.f, 0.f};
    #pragma unroll
    for (int a = 0; a < 4; ++a)
        #pragma unroll
        for (int b = 0; b < 2; ++b) { acc0[a][b] = zz; acc1[a][b] = zz; }

    for (int cl = cl0; cl < cl1; ++cl) {
        int cg = cBase + cl;
        int kid = cg >> 2;
        int kd = kid/25, rr = kid - kd*25, kh = rr/5, kw = rr - kh*5;
        int koff = (kd*400 + kh*20 + kw)*256 + (cg & 3)*64;

        __syncthreads();
        {
            const char* wsrc = (const char*)Wb + ((size_t)(m*NSt + cl))*32768 + w*8192;
            #pragma unroll
            for (int i = 0; i < 8; ++i)
                gload16(wsrc + i*1024 + l*16, lds + w*8192 + i*1024);
            #pragma unroll
            for (int i = 0; i < 4; ++i)
                gload16(preP[i] + koff, lds + 32768 + w*4096 + i*1024);
        }
        __syncthreads();

        #pragma unroll
        for (int ks = 0; ks < 2; ++ks) {
            const int kx = ks ? 64 : 0;
            h8 af[2][4], bf[2][2];
            #pragma unroll
            for (int v = 0; v < 2; ++v) {
                #pragma unroll
                for (int mf = 0; mf < 4; ++mf)
                    af[v][mf] = *(const h8*)(lds + v*16384 + (wm*64 + mf*16)*128 + (plF ^ kx));
                #pragma unroll
                for (int nf = 0; nf < 2; ++nf)
                    bf[v][nf] = *(const h8*)(lds + 32768 + v*8192 + (wn*32 + nf*16)*128 + (plF ^ kx));
            }
            #pragma unroll
            for (int mf = 0; mf < 4; ++mf)
                #pragma unroll
                for (int nf = 0; nf < 2; ++nf) {
                    acc0[mf][nf] = __builtin_amdgcn_mfma_f32_16x16x32_f16(af[0][mf], bf[0][nf], acc0[mf][nf], 0,0,0);
                    acc1[mf][nf] = __builtin_amdgcn_mfma_f32_16x16x32_f16(af[0][mf], bf[1][nf], acc1[mf][nf], 0,0,0);
                    acc1[mf][nf] = __builtin_amdgcn_mfma_f32_16x16x32_f16(af[1][mf], bf[0][nf], acc1[mf][nf], 0,0,0);
                }
        }
    }

    const float s1 = 4.8828125e-04f;
    float* oz = h2p + (size_t)blockIdx.z * 2097152;
    #pragma unroll
    for (int mf = 0; mf < 4; ++mf)
        #pragma unroll
        for (int nf = 0; nf < 2; ++nf) {
            f32x4 r = acc0[mf][nf] + s1*acc1[mf][nf];
            int co = m*128 + wm*64 + mf*16 + ((l>>4)<<2);
            int n  = n0 + wn*32 + nf*16 + (l&15);
            int b2 = n >> 12, so = n & 4095;
            #pragma unroll
            for (int rr = 0; rr < 4; ++rr) {
                size_t idx = ((size_t)(b2*256 + co + rr))*4096 + so;
                if (accum) oz[idx] += r[rr];
                else       oz[idx]  = r[rr];
            }
        }
}

// ---------------- h2 epilogue: slab0 += slab1 + slab2 + bias, relu (in place) ----------------
__global__ __launch_bounds__(256)
void k_h2epi(float* __restrict__ p0, const float* __restrict__ bias)
{
    int g = blockIdx.x*256 + threadIdx.x;   // 524,288 float4 groups
    int e = g*4;
    int co = (e >> 12) & 255;
    float4 a = *(const float4*)(p0 + e);
    float4 b = *(const float4*)(p0 + 2097152 + e);
    float4 c = *(const float4*)(p0 + 4194304 + e);
    float bb = bias[co];
    float4 r;
    r.x = fmaxf(a.x + b.x + c.x + bb, 0.f);
    r.y = fmaxf(a.y + b.y + c.y + bb, 0.f);
    r.z = fmaxf(a.z + b.z + c.z + bb, 0.f);
    r.w = fmaxf(a.w + b.w + c.w + bb, 0.f);
    *(float4*)(p0 + e) = r;
}

// ---------------- fp32 implicit-GEMM conv (primary caps), partial-K output slabs ----------------
template<int CIN, int KD, int STRIDE, int IND, int OUTD>
__global__ __launch_bounds__(256, 2)
void k_gemm_conv(const float* __restrict__ in, const float* __restrict__ W,
                 float* __restrict__ out)
{
    constexpr int KD2  = KD*KD;
    constexpr int K3   = KD*KD*KD;
    constexpr int IND2 = IND*IND;
    constexpr int IND3 = IND2*IND;
    constexpr int OUT2 = OUTD*OUTD;
    constexpr int OUT3 = OUT2*OUTD;
    constexpr int KTOT = CIN*K3;
    constexpr int NCH  = KTOT/16;

    const int tid  = threadIdx.x;
    const int mIdx = tid >> 4;
    const int nIdx = tid & 15;
    const int n0   = blockIdx.x * 128;
    const int co0  = blockIdx.y * 128;
    const int per  = NCH / (int)gridDim.z;
    const int c0   = blockIdx.z * per;
    const int c1   = c0 + per;

    __shared__ float As[16][132];
    __shared__ float Bs[16][132];

    const int nB    = n0 + (tid & 127);
    const int kHalf = tid >> 7;
    int bB = nB / OUT3;
    int sB = nB - bB*OUT3;
    int xB = sB / OUT2;
    int yB = (sB / OUTD) % OUTD;
    int zB = sB % OUTD;
    const float* inB = in + (size_t)bB*CIN*IND3
                          + (xB*STRIDE)*IND2 + (yB*STRIDE)*IND + (zB*STRIDE);
    const int cB  = tid & 127;
    const int qB  = cB >> 2;
    const int bpos = ((((qB & 1) << 4) | (qB >> 1)) << 2) | (cB & 3);

    const int aCo = tid >> 2;
    const int aKq = (tid & 3) * 4;
    const int qA  = aCo >> 2;
    const int apos = ((((qA & 1) << 4) | (qA >> 1)) << 2) | (aCo & 3);
    const float* Wr0 = W + (size_t)(co0 + aCo)*KTOT + aKq;
    const float* Wr1 = W + (size_t)(co0 + 64 + aCo)*KTOT + aKq;

    float acc[8][8];
    #pragma unroll
    for (int i = 0; i < 8; ++i)
        #pragma unroll
        for (int j = 0; j < 8; ++j) acc[i][j] = 0.f;

    for (int c = c0; c < c1; ++c) {
        const int kb = c*16;
        float4 a0 = *(const float4*)(Wr0 + kb);
        float4 a1 = *(const float4*)(Wr1 + kb);
        float bv[8];
        #pragma unroll
        for (int p = 0; p < 8; ++p) {
            int k  = kb + p*2 + kHalf;
            int ci = k / K3;
            int r  = k - ci*K3;
            int kd = r / KD2;
            int r2 = r - kd*KD2;
            int kh = r2 / KD;
            int kw = r2 - kh*KD;
            bv[p] = inB[ci*IND3 + kd*IND2 + kh*IND + kw];
        }
        __syncthreads();
        As[aKq+0][apos] = a0.x; As[aKq+1][apos] = a0.y;
        As[aKq+2][apos] = a0.z; As[aKq+3][apos] = a0.w;
        As[aKq+0][apos+32] = a1.x; As[aKq+1][apos+32] = a1.y;
        As[aKq+2][apos+32] = a1.z; As[aKq+3][apos+32] = a1.w;
        #pragma unroll
        for (int p = 0; p < 8; ++p) Bs[p*2 + kHalf][bpos] = bv[p];
        __syncthreads();
        #pragma unroll
        for (int kk = 0; kk < 16; ++kk) {
            float af[8], bf[8];
            *(float4*)&af[0] = *(const float4*)&As[kk][mIdx*4];
            *(float4*)&af[4] = *(const float4*)&As[kk][64 + mIdx*4];
            *(float4*)&bf[0] = *(const float4*)&Bs[kk][nIdx*4];
            *(float4*)&bf[4] = *(const float4*)&Bs[kk][64 + nIdx*4];
            #pragma unroll
            for (int i = 0; i < 8; ++i)
                #pragma unroll
                for (int j = 0; j < 8; ++j)
                    acc[i][j] += af[i]*bf[j];
        }
    }

    float* oz = out + (size_t)blockIdx.z * (2*256*OUT3);
    #pragma unroll
    for (int j = 0; j < 8; ++j) {
        int n = n0 + nIdx*8 + j;
        int b = n / OUT3;
        int s = n - b*OUT3;
        float* o = oz + ((size_t)b*256 + co0 + mIdx*8)*OUT3 + s;
        #pragma unroll
        for (int i = 0; i < 8; ++i)
            o[(size_t)i*OUT3] = acc[i][j];
    }
}

// ---------------- prim reduce stage 1: 216 slabs -> 8 partial slabs ----------------
__global__ __launch_bounds__(256)
void k_pr1(const float* __restrict__ pp, float* __restrict__ out1)
{
    int e = blockIdx.x*256 + threadIdx.x;   // 32768 elements, grid.x = 128
    int y = blockIdx.y;                      // 8 groups of 27 slabs
    const float* src = pp + (size_t)y*27*32768 + e;
    float a = 0.f;
    #pragma unroll
    for (int j = 0; j < 27; ++j) a += src[(size_t)j*32768];
    out1[y*32768 + e] = a;
}

// ---------------- prim reduce stage 2: 8 partials + bias + squash -> u ----------------
__global__ __launch_bounds__(256)
void k_pr2(const float* __restrict__ out1, const float* __restrict__ pbias,
           float* __restrict__ u)
{
    int g = blockIdx.x*256 + threadIdx.x;      // B*2048 = 4096
    int b = g >> 11;
    int i = g & 2047;
    int cap = i >> 6;
    int s   = i & 63;
    float vals[8];
    float sq = 0.f;
    #pragma unroll
    for (int c = 0; c < 8; ++c) {
        size_t base = ((size_t)(b*256) + cap*8 + c)*64 + s;
        float a = 0.f;
        #pragma unroll
        for (int j = 0; j < 8; ++j) a += out1[(size_t)j*32768 + base];
        float x = a + pbias[cap*8 + c];
        vals[c] = x;
        sq += x*x;
    }
    float scale = (sq / (1.f + sq)) / sqrtf(sq + 1e-8f);
    #pragma unroll
    for (int c = 0; c < 8; ++c) u[(size_t)g*8 + c] = vals[c]*scale;
}

// ---------------- routing (i0 split = 8) ----------------
__global__ __launch_bounds__(256)
void k_route(const float* __restrict__ Wr, const float* __restrict__ u,
             float* __restrict__ s_buf)
{
    int j  = blockIdx.x;          // 50
    int i0 = blockIdx.y * 256;    // 8 splits
    __shared__ float us[2*256*8]; // 16 KB
    for (int idx = threadIdx.x; idx < 4096; idx += 256) {
        int b = idx >> 11;
        us[idx] = u[(size_t)b*16384 + (size_t)i0*8 + (idx & 2047)];
    }
    __syncthreads();
    int tid = threadIdx.x;
    int cc  = tid & 7;
    const float* Wj = Wr + (size_t)j*2048*512 + (size_t)i0*512;
    float a00 = 0.f, a01 = 0.f, a10 = 0.f, a11 = 0.f;
    for (int i = 0; i < 256; ++i) {
        float w0 = Wj[(size_t)i*512 + tid];
        float w1 = Wj[(size_t)i*512 + tid + 256];
        float u0 = us[i*8 + cc];
        float u1 = us[2048 + i*8 + cc];
        a00 += w0*u0; a01 += w1*u0; a10 += w0*u1; a11 += w1*u1;
    }
    __syncthreads();
    float* red = us;
    red[tid] = a00; red[256 + tid] = a01; red[512 + tid] = a10; red[768 + tid] = a11;
    __syncthreads();
    if (tid < 128) {
        int b = tid >> 6, d = tid & 63;
        const float* rb = red + b*512 + (d >> 5)*256 + (d & 31)*8;
        float s = 0.f;
        #pragma unroll
        for (int c2 = 0; c2 < 8; ++c2) s += rb[c2];
        atomicAdd(&s_buf[((size_t)b*50 + j)*64 + d], s * (1.0f/50.0f));
    }
}

// ---------------- squash v ----------------
__global__ __launch_bounds__(64)
void k_squash_v(const float* __restrict__ s_buf, float* __restrict__ v_buf)
{
    int row = blockIdx.x;
    int d   = threadIdx.x;
    float s  = s_buf[row*64 + d];
    float sq = s*s;
    #pragma unroll
    for (int o = 32; o > 0; o >>= 1) sq += __shfl_xor(sq, o);
    float scale = (sq / (1.f + sq)) / sqrtf(sq + 1e-8f);
    v_buf[row*64 + d] = s*scale;
}

// ---------------- dec1 -> fp16x2 channel-last limbs ----------------
__global__ __launch_bounds__(256)
void k_dec1(const float* __restrict__ v, const float* __restrict__ W,
            const float* __restrict__ bias, _Float16* __restrict__ d1cl)
{
    int g  = blockIdx.x*256 + threadIdx.x;  // 442368
    int co = g & 127;
    int t  = g >> 7;
    int o  = t % 1728;
    int b  = t / 1728;
    int ox = o / 144, oy = (o/12) % 12, oz = o % 12;
    int ix = ox/3, ka = ox - 3*ix;
    int iy = oy/3, kb = oy - 3*iy;
    int iz = oz/3, kc = oz - 3*iz;
    int widx = ka*9 + kb*3 + kc;
    int sidx = ix*16 + iy*4 + iz;
    float s = 0.f;
    for (int ci = 0; ci < 50; ++ci)
        s += v[((size_t)b*50 + ci)*64 + sidx] * W[((size_t)ci*128 + co)*27 + widx];
    float x = fmaxf(s + bias[co], 0.f);
    _Float16 a0, a1; split2(x, a0, a1);
    size_t base = (size_t)(b*1728 + o)*128 + co;
    d1cl[base]         = a0;
    d1cl[base + D1_PL] = a1;
}

// ---------------- dec2 MFMA, PARITY-DECOMPOSED (4-wave), per co-half ----------------
__global__ __launch_bounds__(256, 3)
void k_dec2p(const _Float16* __restrict__ d1cl, const char* __restrict__ Wb,
             const float* __restrict__ bias, float* __restrict__ out, int coBase)
{
    extern __shared__ char lds[];           // A 32KB + B 16KB
    const int tid = threadIdx.x;
    const int l   = tid & 63;
    const int w   = tid >> 6;
    const int wm  = w >> 1, wn = w & 1;
    const int cls = blockIdx.z;
    const int px  = (cls >> 2) & 1, py = (cls >> 1) & 1, pz = cls & 1;
    const int n0  = blockIdx.x * 64;        // class-local n over 3456
    const int m   = blockIdx.y;
    const int mG  = (coBase >> 7) + m;

    int cb = 0;
    for (int c = 0; c < cls; ++c) cb += 2 << __popc(c);
    const int nch = 2 << __popc(cls);

    const int nRow = tid & 63;
    const int q    = tid >> 6;
    const int nT   = n0 + nRow;
    const int b2s  = nT / 1728;
    const int rs   = nT - b2s*1728;
    const int oxh  = rs/144, oyh = (rs/12)%12, ozh = rs%12;
    const int posB = b2s*1728;
    const int bw0 = 32768 + nRow*128 + ((q*32)      ^ ((nRow&7)<<4));
    const int bw1 = 32768 + nRow*128 + ((q*32 + 16) ^ ((nRow&7)<<4));

    const int swz = (l & 7) << 4;
    const int qo  = (l >> 4) << 4;
    const int plF = (l & 15)*128 + (qo ^ (swz & 0x30)) + (swz & 0x40);

    f32x4 acc0[4][2], acc1[4][2];
    const f32x4 zz = {0.f, 0.f, 0.f, 0.f};
    #pragma unroll
    for (int a = 0; a < 4; ++a)
        #pragma unroll
        for (int b = 0; b < 2; ++b) { acc0[a][b] = zz; acc1[a][b] = zz; }

    const h8 z8 = {};
    for (int c = 0; c < nch; ++c) {
        int ti = c >> 1, ch = c & 1;
        int kd, kh, kw;
        tapDecode(cls, ti, kd, kh, kw);
        int txh = oxh + (px && kd == 0);
        int tyh = oyh + (py && kh == 0);
        int tzh = ozh + (pz && kw == 0);
        bool ok = (txh < 12) && (tyh < 12) && (tzh < 12);
        const _Float16* src = d1cl + (size_t)(posB + txh*144 + tyh*12 + tzh)*128
                                   + ch*64 + q*16;
        h8 b0a = *(const h8*)(src);
        h8 b0b = *(const h8*)(src + 8);
        h8 b1a = *(const h8*)(src + D1_PL);
        h8 b1b = *(const h8*)(src + D1_PL + 8);

        __syncthreads();
        {
            const char* wsrc = (const char*)Wb + ((size_t)(mG*54 + cb + c))*32768 + w*8192;
            #pragma unroll
            for (int i = 0; i < 8; ++i)
                gload16(wsrc + i*1024 + l*16, lds + w*8192 + i*1024);
        }
        *(h8*)(lds + bw0)         = ok ? b0a : z8;
        *(h8*)(lds + bw1)         = ok ? b0b : z8;
        *(h8*)(lds + 8192 + bw0)  = ok ? b1a : z8;
        *(h8*)(lds + 8192 + bw1)  = ok ? b1b : z8;
        __syncthreads();

        #pragma unroll
        for (int ks = 0; ks < 2; ++ks) {
            const int kx = ks ? 64 : 0;
            h8 af[2][4], bf[2][2];
            #pragma unroll
            for (int v = 0; v < 2; ++v) {
                #pragma unroll
                for (int mf = 0; mf < 4; ++mf)
                    af[v][mf] = *(const h8*)(lds + v*16384 + (wm*64 + mf*16)*128 + (plF ^ kx));
                #pragma unroll
                for (int nf = 0; nf < 2; ++nf)
                    bf[v][nf] = *(const h8*)(lds + 32768 + v*8192 + (wn*32 + nf*16)*128 + (plF ^ kx));
            }
            #pragma unroll
            for (int mf = 0; mf < 4; ++mf)
                #pragma unroll
                for (int nf = 0; nf < 2; ++nf) {
                    acc0[mf][nf] = __builtin_amdgcn_mfma_f32_16x16x32_f16(af[0][mf], bf[0][nf], acc0[mf][nf], 0,0,0);
                    acc1[mf][nf] = __builtin_amdgcn_mfma_f32_16x16x32_f16(af[0][mf], bf[1][nf], acc1[mf][nf], 0,0,0);
                    acc1[mf][nf] = __builtin_amdgcn_mfma_f32_16x16x32_f16(af[1][mf], bf[0][nf], acc1[mf][nf], 0,0,0);
                }
        }
    }

    const float s1 = 4.8828125e-04f;
    #pragma unroll
    for (int mf = 0; mf < 4; ++mf)
        #pragma unroll
        for (int nf = 0; nf < 2; ++nf) {
            f32x4 r = acc0[mf][nf] + s1*acc1[mf][nf];
            int coL = m*128 + wm*64 + mf*16 + ((l>>4)<<2);
            int coG = coBase + coL;
            int nT2 = n0 + wn*32 + nf*16 + (l&15);
            int b2  = nT2 / 1728;
            int r2  = nT2 - b2*1728;
            int ax  = r2/144, ay = (r2/12)%12, az = r2%12;
            int outIdx = b2*13824 + (2*ax + px)*576 + (2*ay + py)*24 + (2*az + pz);
            float4 v;
            v.x = fmaxf(r[0] + bias[coG + 0], 0.f);
            v.y = fmaxf(r[1] + bias[coG + 1], 0.f);
            v.z = fmaxf(r[2] + bias[coG + 2], 0.f);
            v.w = fmaxf(r[3] + bias[coG + 3], 0.f);
            *(float4*)(out + (size_t)outIdx*256 + coL) = v;
        }
}

// ---------------- final gather (per co-half) ----------------
__global__ __launch_bounds__(256)
void k_gather(const float* __restrict__ d2h, const int* __restrict__ vid,
              float* __restrict__ out, int colOff)
{
    int g  = blockIdx.x*256 + threadIdx.x;   // B*P*64 float4 units
    int qq = g & 63;
    int bp = g >> 6;
    int v  = vid[bp];
    int b  = bp >> 13;
    float4 val = *(const float4*)&d2h[((size_t)(b*N3 + v))*256 + qq*4];
    *(float4*)&out[(size_t)bp*512 + colOff + qq*4] = val;
}

extern "C" void kernel_launch(void* const* d_in, const int* in_sizes, int n_in,
                              void* d_out, int out_size, void* d_ws, size_t ws_size,
                              hipStream_t stream)
{
    (void)in_sizes; (void)n_in; (void)out_size; (void)ws_size;
    const float* pcl  = (const float*)d_in[0];
    const float* feat = (const float*)d_in[1];
    const float* c1w  = (const float*)d_in[3];
    const float* c1b  = (const float*)d_in[4];
    const float* c2w  = (const float*)d_in[5];
    const float* c2b  = (const float*)d_in[6];
    const float* pw   = (const float*)d_in[7];
    const float* pb   = (const float*)d_in[8];
    const float* rw   = (const float*)d_in[9];
    const float* d1w  = (const float*)d_in[10];
    const float* d1b_ = (const float*)d_in[11];
    const float* d2w  = (const float*)d_in[12];
    const float* d2b  = (const float*)d_in[13];

    char* ws = (char*)d_ws;
    float*     meshS  = (float*)(ws + MESHS_OFF);
    _Float16*  m16    = (_Float16*)(ws + M16_OFF);
    _Float16*  h1cl   = (_Float16*)(ws + H1CL_OFF);
    char*      Wb     = ws + WB_OFF;
    char*      Wb2c   = ws + WB2C_OFF;
    float*     h2p    = (float*)(ws + H2P_OFF);
    float*     p_part = (float*)(ws + PPART_OFF);
    float*     pr1    = (float*)(ws + PR1_OFF);
    char*      Wbd    = ws + WBD_OFF;
    float*     d2h    = (float*)(ws + D2H_OFF);
    _Float16*  d1cl   = (_Float16*)(ws + D1CL_OFF);
    int*       vid    = (int*)(ws + VID_OFF);
    float*     u_buf  = (float*)(ws + UBUF_OFF);
    float*     s_buf  = (float*)(ws + SBUF_OFF);
    float*     v_buf  = (float*)(ws + VBUF_OFF);

    k_vid<<<dim3(B_), dim3(256), 0, stream>>>(pcl, vid);

    hipMemsetAsync(meshS, 0, 14155776, stream);
    k_scatter<<<dim3(8192), dim3(256), 0, stream>>>(feat, vid, meshS);
    k_meshsplit<<<dim3(3456), dim3(256), 0, stream>>>(meshS, m16);

    // conv1
    k_splitw1<<<dim3(16000), dim3(256), 0, stream>>>(c1w, Wb);
    k_conv1<<<dim3(250, 2), dim3(256), 49152, stream>>>(m16, Wb, c1b, h1cl);

    // conv2: two half-K weight stages, each z=3 split-K -> 3 partial slabs
    k_splitw2<<<dim3(15872), dim3(256), 0, stream>>>(c2w, Wb2c, 0, 248);
    k_conv2<<<dim3(128, 2, 3), dim3(256), 49152, stream>>>(h1cl, Wb2c, h2p, 0, 248, 0);
    k_splitw2<<<dim3(16128), dim3(256), 0, stream>>>(c2w, Wb2c, 248, 252);
    k_conv2<<<dim3(128, 2, 3), dim3(256), 49152, stream>>>(h1cl, Wb2c, h2p, 248, 252, 1);
    k_h2epi<<<dim3(2048), dim3(256), 0, stream>>>(h2p, c2b);

    // primary caps: fp32 GEMM -> 216 partial slabs, then 2-stage wide reduce
    k_gemm_conv<256,9,2,16,4><<<dim3(1, 2, 216), dim3(256), 0, stream>>>(h2p, pw, p_part);
    k_pr1<<<dim3(128, 8), dim3(256), 0, stream>>>(p_part, pr1);
    k_pr2<<<dim3(16), dim3(256), 0, stream>>>(pr1, pb, u_buf);

    hipMemsetAsync(s_buf, 0, 25600, stream);
    k_route<<<dim3(50, 8), dim3(256), 0, stream>>>(rw, u_buf, s_buf);
    k_squash_v<<<dim3(100), dim3(64), 0, stream>>>(s_buf, v_buf);

    k_dec1<<<dim3(1728), dim3(256), 0, stream>>>(v_buf, d1w, d1b_, d1cl);

    // dec2 weights, parity-grouped (Wbd overlaps h2p region, dead by then)
    k_splitwd2p<<<dim3(6912), dim3(256), 0, stream>>>(d2w, Wbd);

    k_dec2p<<<dim3(54, 2, 8), dim3(256), 49152, stream>>>(d1cl, Wbd, d2b, d2h, 0);
    k_gather<<<dim3(4096), dim3(256), 0, stream>>>(d2h, vid, (float*)d_out, 0);
    k_dec2p<<<dim3(54, 2, 8), dim3(256), 49152, stream>>>(d1cl, Wbd, d2b, d2h, 256);
    k_gather<<<dim3(4096), dim3(256), 0, stream>>>(d2h, vid, (float*)d_out, 256);
}

// Round 18
// 1281.336 us; speedup vs baseline: 1.3122x; 1.0483x over previous
//
#include <hip/hip_runtime.h>
#include <cstdint>
#include <cstddef>

typedef _Float16 h8 __attribute__((ext_vector_type(8)));
typedef _Float16 h4 __attribute__((ext_vector_type(4)));
typedef float    f32x4 __attribute__((ext_vector_type(4)));

#define B_   2
#define P_   8192
#define NVOX 24
#define N3   13824

// ---- workspace layout (bytes). Peak 61.2 MB < 63.9 MB proven bound. ----
#define MESHS_OFF 0ull
#define M16_OFF   14155776ull
#define H1CL_OFF  28311552ull
#define WB_OFF    44695552ull
#define WB2C_OFF  44695552ull
#define H2P_OFF   0ull
#define PPART_OFF 25165824ull
#define PR1_OFF   53477376ull
#define WBD_OFF   0ull
#define D2H_OFF   10616832ull
#define D1CL_OFF  38928384ull
#define VID_OFF   63504384ull
#define UBUF_OFF  63700992ull
#define SBUF_OFF  63832064ull
#define VBUF_OFF  63857664ull

#define M16_PL   3538944ull     // mesh16 plane stride (elements)
#define H1_PL    4096000ull     // h1cl plane stride (elements)
#define D1_PL    442368ull      // d1cl plane stride (elements)

// ---------------- helpers ----------------
__device__ inline void split2(float x, _Float16& a0, _Float16& a1)
{
    a0 = (_Float16)x;
    float r = x - (float)a0;
    a1 = (_Float16)(r * 2048.0f);
}

__device__ inline void gload16(const void* g, void* l)
{
    __builtin_amdgcn_global_load_lds(
        (const __attribute__((address_space(1))) char*)g,
        (__attribute__((address_space(3))) char*)l, 16, 0, 0);
}

// parity-class helpers for dec2
__device__ inline void tapDecode(int cls, int ti, int& kd, int& kh, int& kw)
{
    int px = (cls >> 2) & 1, py = (cls >> 1) & 1, pz = cls & 1;
    int tiz = pz ? (ti & 1) : 0;
    int t1  = ti >> pz;
    int tiy = py ? (t1 & 1) : 0;
    int tix = t1 >> py;
    kd = px ? tix*2 : 1;
    kh = py ? tiy*2 : 1;
    kw = pz ? tiz*2 : 1;
}

// ---------------- voxel ids ----------------
__global__ __launch_bounds__(256)
void k_vid(const float* __restrict__ pcl, int* __restrict__ vid)
{
    int b = blockIdx.x;
    const float* pb = pcl + (size_t)b * P_ * 3;
    float mn[3] = {3e38f, 3e38f, 3e38f};
    float mx[3] = {-3e38f, -3e38f, -3e38f};
    for (int p = threadIdx.x; p < P_; p += 256) {
        #pragma unroll
        for (int d = 0; d < 3; ++d) {
            float v = pb[p*3 + d];
            mn[d] = fminf(mn[d], v);
            mx[d] = fmaxf(mx[d], v);
        }
    }
    __shared__ float red[6][256];
    #pragma unroll
    for (int d = 0; d < 3; ++d) { red[d][threadIdx.x] = mn[d]; red[3+d][threadIdx.x] = mx[d]; }
    __syncthreads();
    for (int s = 128; s > 0; s >>= 1) {
        if (threadIdx.x < (unsigned)s) {
            #pragma unroll
            for (int d = 0; d < 3; ++d) {
                red[d][threadIdx.x]   = fminf(red[d][threadIdx.x],   red[d][threadIdx.x + s]);
                red[3+d][threadIdx.x] = fmaxf(red[3+d][threadIdx.x], red[3+d][threadIdx.x + s]);
            }
        }
        __syncthreads();
    }
    float mn0 = red[0][0], mn1 = red[1][0], mn2 = red[2][0];
    float dd0 = red[3][0] - mn0 + 1e-9f;
    float dd1 = red[4][0] - mn1 + 1e-9f;
    float dd2 = red[5][0] - mn2 + 1e-9f;
    for (int p = threadIdx.x; p < P_; p += 256) {
        float fx = (pb[p*3+0] - mn0) / dd0 * 24.0f;
        float fy = (pb[p*3+1] - mn1) / dd1 * 24.0f;
        float fz = (pb[p*3+2] - mn2) / dd2 * 24.0f;
        int ix = (int)floorf(fx); ix = ix < 0 ? 0 : (ix > 23 ? 23 : ix);
        int iy = (int)floorf(fy); iy = iy < 0 ? 0 : (iy > 23 ? 23 : iy);
        int iz = (int)floorf(fz); iz = iz < 0 ? 0 : (iz > 23 ? 23 : iz);
        vid[b*P_ + p] = ix*576 + iy*24 + iz;
    }
}

// ---------------- scatter-add point features -> meshS (B, N3, 128) ----------------
__global__ __launch_bounds__(256)
void k_scatter(const float* __restrict__ feat, const int* __restrict__ vid,
               float* __restrict__ meshS)
{
    int g = blockIdx.x*256 + threadIdx.x;      // B*P*C = 2,097,152
    int c  = g & 127;
    int bp = g >> 7;
    int v  = vid[bp];
    int b  = bp >> 13;
    atomicAdd(&meshS[((size_t)b*N3 + v)*128 + c], feat[g]);
}

// ---------------- mesh fp32 -> fp16x2 limb planes ----------------
__global__ __launch_bounds__(256)
void k_meshsplit(const float* __restrict__ meshS, _Float16* __restrict__ m16)
{
    int g = blockIdx.x*256 + threadIdx.x;   // 884,736 float4 groups
    int e = g*4;
    float4 a = *(const float4*)(meshS + e);
    h4 v0, v1;
    float xs[4] = {a.x, a.y, a.z, a.w};
    #pragma unroll
    for (int j = 0; j < 4; ++j) {
        _Float16 t0, t1; split2(xs[j], t0, t1);
        v0[j] = t0; v1[j] = t1;
    }
    *(h4*)(m16 + e)          = v0;
    *(h4*)(m16 + M16_PL + e) = v1;
}

// ---------------- pre-split conv1 weights ----------------
__global__ __launch_bounds__(256)
void k_splitw1(const float* __restrict__ W, char* __restrict__ Wb)
{
    int g = blockIdx.x*256 + threadIdx.x;   // 4,096,000
    int el   = g & 8191;
    int tile = g >> 13;                      // m*250 + c
    int m = tile / 250, c = tile - m*250;
    int co = el >> 6, kl = el & 63;
    int kg = c*64 + kl;
    int kid = kg >> 7, ci = kg & 127;
    float x = W[((size_t)((m*128 + co)*128 + ci))*125 + kid];
    _Float16 a0, a1; split2(x, a0, a1);
    char* dst = Wb + (size_t)tile*32768 + (co*128 + ((kl*2) ^ ((co&7)<<4)));
    *(_Float16*)(dst)         = a0;
    *(_Float16*)(dst + 16384) = a1;
}

// ---------------- pre-split conv2 weights (half-K at a time) ----------------
__global__ __launch_bounds__(256)
void k_splitw2(const float* __restrict__ W, char* __restrict__ Wb, int cBase, int NC)
{
    int g = blockIdx.x*256 + threadIdx.x;   // 2*NC*8192
    int el   = g & 8191;
    int tile = g >> 13;                      // m*NC + cl
    int m = tile / NC, cl = tile - m*NC;
    int c = cBase + cl;
    int co = el >> 6, kl = el & 63;
    int kg = c*64 + kl;
    int kid = kg >> 8, ci = kg & 255;
    float x = W[((size_t)((m*128 + co)*256 + ci))*125 + kid];
    _Float16 a0, a1; split2(x, a0, a1);
    char* dst = Wb + (size_t)tile*32768 + (co*128 + ((kl*2) ^ ((co&7)<<4)));
    *(_Float16*)(dst)         = a0;
    *(_Float16*)(dst + 16384) = a1;
}

// ---------------- pre-split dec2 weights, PARITY-GROUPED ----------------
__global__ __launch_bounds__(256)
void k_splitwd2p(const float* __restrict__ W, char* __restrict__ Wb)
{
    int g = blockIdx.x*256 + threadIdx.x;   // 216*8192 = 1,769,472
    int el   = g & 8191;
    int tile = g >> 13;                      // mG*54 + chunkG
    int mG = tile / 54, chunkG = tile - mG*54;
    int co = el >> 6, kl = el & 63;
    int rem = chunkG, cls = 0;
    for (int c = 0; c < 8; ++c) {
        int cc = 2 << __popc(c);
        if (rem < cc) { cls = c; break; }
        rem -= cc;
    }
    int k  = rem*64 + kl;
    int ti = k >> 7;
    int ci = k & 127;
    int kd, kh, kw;
    tapDecode(cls, ti, kd, kh, kw);
    int kid = kd*9 + kh*3 + kw;
    float x = W[((size_t)ci*512 + (mG*128 + co))*27 + kid];
    _Float16 a0, a1; split2(x, a0, a1);
    char* dst = Wb + (size_t)tile*32768 + (co*128 + ((kl*2) ^ ((co&7)<<4)));
    *(_Float16*)(dst)         = a0;
    *(_Float16*)(dst + 16384) = a1;
}

// ---------------- conv1 MFMA (proven r12 structure) ----------------
__global__ __launch_bounds__(256, 3)
void k_conv1(const _Float16* __restrict__ m16, const char* __restrict__ Wb,
             const float* __restrict__ bias, _Float16* __restrict__ h1cl)
{
    extern __shared__ char lds[];           // A 32KB + B 16KB = 48KB
    const int tid = threadIdx.x;
    const int l   = tid & 63;
    const int w   = tid >> 6;
    const int wm  = w >> 1, wn = w & 1;
    const int n0  = blockIdx.x * 64;
    const int m   = blockIdx.y;

    const _Float16* preP[4];
    #pragma unroll
    for (int i = 0; i < 4; ++i) {
        int g   = w*4096 + i*1024 + l*16;
        int ver = g >> 13;
        int dd  = g & 8191;
        int nl  = dd >> 7;
        int lg  = (dd & 127) ^ ((nl & 7) << 4);
        int klocal = lg >> 1;
        int n  = n0 + nl;
        int b2 = n / 8000;
        int so = n - b2*8000;
        int x = so/400, y = (so/20)%20, z = so%20;
        preP[i] = m16 + (size_t)ver*M16_PL
                      + ((size_t)(b2*13824 + x*576 + y*24 + z))*128 + klocal;
    }

    const int swz = (l & 7) << 4;
    const int qo  = (l >> 4) << 4;
    const int plF = (l & 15)*128 + (qo ^ (swz & 0x30)) + (swz & 0x40);

    f32x4 acc0[4][2], acc1[4][2];
    const f32x4 zz = {0.f, 0.f, 0.f, 0.f};
    #pragma unroll
    for (int a = 0; a < 4; ++a)
        #pragma unroll
        for (int b = 0; b < 2; ++b) { acc0[a][b] = zz; acc1[a][b] = zz; }

    for (int c = 0; c < 250; ++c) {
        int kid = c >> 1;
        int kd = kid/25, rr = kid - kd*25, kh = rr/5, kw = rr - kh*5;
        int koff = (kd*576 + kh*24 + kw)*128 + (c & 1)*64;

        __syncthreads();
        {
            const char* wsrc = (const char*)Wb + ((size_t)(m*250 + c))*32768 + w*8192;
            #pragma unroll
            for (int i = 0; i < 8; ++i)
                gload16(wsrc + i*1024 + l*16, lds + w*8192 + i*1024);
            #pragma unroll
            for (int i = 0; i < 4; ++i)
                gload16(preP[i] + koff, lds + 32768 + w*4096 + i*1024);
        }
        __syncthreads();

        #pragma unroll
        for (int ks = 0; ks < 2; ++ks) {
            const int kx = ks ? 64 : 0;
            h8 af[2][4], bf[2][2];
            #pragma unroll
            for (int v = 0; v < 2; ++v) {
                #pragma unroll
                for (int mf = 0; mf < 4; ++mf)
                    af[v][mf] = *(const h8*)(lds + v*16384 + (wm*64 + mf*16)*128 + (plF ^ kx));
                #pragma unroll
                for (int nf = 0; nf < 2; ++nf)
                    bf[v][nf] = *(const h8*)(lds + 32768 + v*8192 + (wn*32 + nf*16)*128 + (plF ^ kx));
            }
            #pragma unroll
            for (int mf = 0; mf < 4; ++mf)
                #pragma unroll
                for (int nf = 0; nf < 2; ++nf) {
                    acc0[mf][nf] = __builtin_amdgcn_mfma_f32_16x16x32_f16(af[0][mf], bf[0][nf], acc0[mf][nf], 0,0,0);
                    acc1[mf][nf] = __builtin_amdgcn_mfma_f32_16x16x32_f16(af[0][mf], bf[1][nf], acc1[mf][nf], 0,0,0);
                    acc1[mf][nf] = __builtin_amdgcn_mfma_f32_16x16x32_f16(af[1][mf], bf[0][nf], acc1[mf][nf], 0,0,0);
                }
        }
    }

    const float s1 = 4.8828125e-04f;
    #pragma unroll
    for (int mf = 0; mf < 4; ++mf)
        #pragma unroll
        for (int nf = 0; nf < 2; ++nf) {
            f32x4 r = acc0[mf][nf] + s1*acc1[mf][nf];
            int co = m*128 + wm*64 + mf*16 + ((l>>4)<<2);
            int n  = n0 + wn*32 + nf*16 + (l&15);
            size_t base = (size_t)n*256 + co;
            h4 v0, v1;
            #pragma unroll
            for (int rr = 0; rr < 4; ++rr) {
                float x = fmaxf(r[rr] + bias[co + rr], 0.f);
                _Float16 t0, t1; split2(x, t0, t1);
                v0[rr] = t0; v1[rr] = t1;
            }
            *(h4*)(h1cl + base)         = v0;
            *(h4*)(h1cl + H1_PL + base) = v1;
        }
}

// ---------------- conv2 MFMA: 128M x 128N block, 4 waves (64x64 each), z-split ----------------
// LDS: A 32KB (2 limbs x [128co][64k]) + B 32KB (2 limbs x [128n][64k]) = 64KB.
__global__ __launch_bounds__(256, 2)
void k_conv2(const _Float16* __restrict__ h1cl, const char* __restrict__ Wb,
             float* __restrict__ h2p, int cBase, int NSt, int accum)
{
    extern __shared__ char lds[];
    const int tid = threadIdx.x;
    const int l   = tid & 63;
    const int w   = tid >> 6;
    const int wm  = w >> 1, wn = w & 1;
    const int n0  = blockIdx.x * 128;
    const int m   = blockIdx.y;
    const int per = (NSt + (int)gridDim.z - 1) / (int)gridDim.z;
    const int cl0 = blockIdx.z * per;
    const int cl1 = min(NSt, cl0 + per);

    // B gload sources (8 per wave), inverse-swizzled per-lane addresses; 32KB B region
    const _Float16* preP[8];
    #pragma unroll
    for (int i = 0; i < 8; ++i) {
        int g   = w*8192 + i*1024 + l*16;   // byte within 32KB B region
        int ver = g >> 14;                   // limb plane (16KB each)
        int dd  = g & 16383;
        int nl  = dd >> 7;                   // n row 0..127
        int lg  = (dd & 127) ^ ((nl & 7) << 4);
        int klocal = lg >> 1;
        int n = n0 + nl;
        int b2 = n >> 12, so = n & 4095;
        int x = so >> 8, y = (so >> 4) & 15, z = so & 15;
        preP[i] = h1cl + (size_t)ver*H1_PL
                       + ((size_t)(b2*8000 + x*400 + y*20 + z))*256 + klocal;
    }

    const int swz = (l & 7) << 4;
    const int qo  = (l >> 4) << 4;
    const int plF = (l & 15)*128 + (qo ^ (swz & 0x30)) + (swz & 0x40);

    f32x4 acc0[4][4], acc1[4][4];
    const f32x4 zz = {0.f, 0.f, 0.f, 0.f};
    #pragma unroll
    for (int a = 0; a < 4; ++a)
        #pragma unroll
        for (int b = 0; b < 4; ++b) { acc0[a][b] = zz; acc1[a][b] = zz; }

    for (int cl = cl0; cl < cl1; ++cl) {
        int cg = cBase + cl;
        int kid = cg >> 2;
        int kd = kid/25, rr = kid - kd*25, kh = rr/5, kw = rr - kh*5;
        int koff = (kd*400 + kh*20 + kw)*256 + (cg & 3)*64;

        __syncthreads();
        {
            const char* wsrc = (const char*)Wb + ((size_t)(m*NSt + cl))*32768 + w*8192;
            #pragma unroll
            for (int i = 0; i < 8; ++i)
                gload16(wsrc + i*1024 + l*16, lds + w*8192 + i*1024);
            #pragma unroll
            for (int i = 0; i < 8; ++i)
                gload16(preP[i] + koff, lds + 32768 + w*8192 + i*1024);
        }
        __syncthreads();

        #pragma unroll
        for (int ks = 0; ks < 2; ++ks) {
            const int kx = ks ? 64 : 0;
            h8 af[2][4], bf[2][4];
            #pragma unroll
            for (int v = 0; v < 2; ++v) {
                #pragma unroll
                for (int mf = 0; mf < 4; ++mf)
                    af[v][mf] = *(const h8*)(lds + v*16384 + (wm*64 + mf*16)*128 + (plF ^ kx));
                #pragma unroll
                for (int nf = 0; nf < 4; ++nf)
                    bf[v][nf] = *(const h8*)(lds + 32768 + v*16384 + (wn*64 + nf*16)*128 + (plF ^ kx));
            }
            #pragma unroll
            for (int mf = 0; mf < 4; ++mf)
                #pragma unroll
                for (int nf = 0; nf < 4; ++nf) {
                    acc0[mf][nf] = __builtin_amdgcn_mfma_f32_16x16x32_f16(af[0][mf], bf[0][nf], acc0[mf][nf], 0,0,0);
                    acc1[mf][nf] = __builtin_amdgcn_mfma_f32_16x16x32_f16(af[0][mf], bf[1][nf], acc1[mf][nf], 0,0,0);
                    acc1[mf][nf] = __builtin_amdgcn_mfma_f32_16x16x32_f16(af[1][mf], bf[0][nf], acc1[mf][nf], 0,0,0);
                }
        }
    }

    const float s1 = 4.8828125e-04f;
    float* oz = h2p + (size_t)blockIdx.z * 2097152;
    #pragma unroll
    for (int mf = 0; mf < 4; ++mf)
        #pragma unroll
        for (int nf = 0; nf < 4; ++nf) {
            f32x4 r = acc0[mf][nf] + s1*acc1[mf][nf];
            int co = m*128 + wm*64 + mf*16 + ((l>>4)<<2);
            int n  = n0 + wn*64 + nf*16 + (l&15);
            int b2 = n >> 12, so = n & 4095;
            #pragma unroll
            for (int rr = 0; rr < 4; ++rr) {
                size_t idx = ((size_t)(b2*256 + co + rr))*4096 + so;
                if (accum) oz[idx] += r[rr];
                else       oz[idx]  = r[rr];
            }
        }
}

// ---------------- h2 epilogue: slab0 += slab1 + slab2 + bias, relu (in place) ----------------
__global__ __launch_bounds__(256)
void k_h2epi(float* __restrict__ p0, const float* __restrict__ bias)
{
    int g = blockIdx.x*256 + threadIdx.x;   // 524,288 float4 groups
    int e = g*4;
    int co = (e >> 12) & 255;
    float4 a = *(const float4*)(p0 + e);
    float4 b = *(const float4*)(p0 + 2097152 + e);
    float4 c = *(const float4*)(p0 + 4194304 + e);
    float bb = bias[co];
    float4 r;
    r.x = fmaxf(a.x + b.x + c.x + bb, 0.f);
    r.y = fmaxf(a.y + b.y + c.y + bb, 0.f);
    r.z = fmaxf(a.z + b.z + c.z + bb, 0.f);
    r.w = fmaxf(a.w + b.w + c.w + bb, 0.f);
    *(float4*)(p0 + e) = r;
}

// ---------------- fp32 implicit-GEMM conv (primary caps), partial-K output slabs ----------------
template<int CIN, int KD, int STRIDE, int IND, int OUTD>
__global__ __launch_bounds__(256, 2)
void k_gemm_conv(const float* __restrict__ in, const float* __restrict__ W,
                 float* __restrict__ out)
{
    constexpr int KD2  = KD*KD;
    constexpr int K3   = KD*KD*KD;
    constexpr int IND2 = IND*IND;
    constexpr int IND3 = IND2*IND;
    constexpr int OUT2 = OUTD*OUTD;
    constexpr int OUT3 = OUT2*OUTD;
    constexpr int KTOT = CIN*K3;
    constexpr int NCH  = KTOT/16;

    const int tid  = threadIdx.x;
    const int mIdx = tid >> 4;
    const int nIdx = tid & 15;
    const int n0   = blockIdx.x * 128;
    const int co0  = blockIdx.y * 128;
    const int per  = NCH / (int)gridDim.z;
    const int c0   = blockIdx.z * per;
    const int c1   = c0 + per;

    __shared__ float As[16][132];
    __shared__ float Bs[16][132];

    const int nB    = n0 + (tid & 127);
    const int kHalf = tid >> 7;
    int bB = nB / OUT3;
    int sB = nB - bB*OUT3;
    int xB = sB / OUT2;
    int yB = (sB / OUTD) % OUTD;
    int zB = sB % OUTD;
    const float* inB = in + (size_t)bB*CIN*IND3
                          + (xB*STRIDE)*IND2 + (yB*STRIDE)*IND + (zB*STRIDE);
    const int cB  = tid & 127;
    const int qB  = cB >> 2;
    const int bpos = ((((qB & 1) << 4) | (qB >> 1)) << 2) | (cB & 3);

    const int aCo = tid >> 2;
    const int aKq = (tid & 3) * 4;
    const int qA  = aCo >> 2;
    const int apos = ((((qA & 1) << 4) | (qA >> 1)) << 2) | (aCo & 3);
    const float* Wr0 = W + (size_t)(co0 + aCo)*KTOT + aKq;
    const float* Wr1 = W + (size_t)(co0 + 64 + aCo)*KTOT + aKq;

    float acc[8][8];
    #pragma unroll
    for (int i = 0; i < 8; ++i)
        #pragma unroll
        for (int j = 0; j < 8; ++j) acc[i][j] = 0.f;

    for (int c = c0; c < c1; ++c) {
        const int kb = c*16;
        float4 a0 = *(const float4*)(Wr0 + kb);
        float4 a1 = *(const float4*)(Wr1 + kb);
        float bv[8];
        #pragma unroll
        for (int p = 0; p < 8; ++p) {
            int k  = kb + p*2 + kHalf;
            int ci = k / K3;
            int r  = k - ci*K3;
            int kd = r / KD2;
            int r2 = r - kd*KD2;
            int kh = r2 / KD;
            int kw = r2 - kh*KD;
            bv[p] = inB[ci*IND3 + kd*IND2 + kh*IND + kw];
        }
        __syncthreads();
        As[aKq+0][apos] = a0.x; As[aKq+1][apos] = a0.y;
        As[aKq+2][apos] = a0.z; As[aKq+3][apos] = a0.w;
        As[aKq+0][apos+32] = a1.x; As[aKq+1][apos+32] = a1.y;
        As[aKq+2][apos+32] = a1.z; As[aKq+3][apos+32] = a1.w;
        #pragma unroll
        for (int p = 0; p < 8; ++p) Bs[p*2 + kHalf][bpos] = bv[p];
        __syncthreads();
        #pragma unroll
        for (int kk = 0; kk < 16; ++kk) {
            float af[8], bf[8];
            *(float4*)&af[0] = *(const float4*)&As[kk][mIdx*4];
            *(float4*)&af[4] = *(const float4*)&As[kk][64 + mIdx*4];
            *(float4*)&bf[0] = *(const float4*)&Bs[kk][nIdx*4];
            *(float4*)&bf[4] = *(const float4*)&Bs[kk][64 + nIdx*4];
            #pragma unroll
            for (int i = 0; i < 8; ++i)
                #pragma unroll
                for (int j = 0; j < 8; ++j)
                    acc[i][j] += af[i]*bf[j];
        }
    }

    float* oz = out + (size_t)blockIdx.z * (2*256*OUT3);
    #pragma unroll
    for (int j = 0; j < 8; ++j) {
        int n = n0 + nIdx*8 + j;
        int b = n / OUT3;
        int s = n - b*OUT3;
        float* o = oz + ((size_t)b*256 + co0 + mIdx*8)*OUT3 + s;
        #pragma unroll
        for (int i = 0; i < 8; ++i)
            o[(size_t)i*OUT3] = acc[i][j];
    }
}

// ---------------- prim reduce stage 1: 216 slabs -> 8 partial slabs ----------------
__global__ __launch_bounds__(256)
void k_pr1(const float* __restrict__ pp, float* __restrict__ out1)
{
    int e = blockIdx.x*256 + threadIdx.x;   // 32768 elements, grid.x = 128
    int y = blockIdx.y;                      // 8 groups of 27 slabs
    const float* src = pp + (size_t)y*27*32768 + e;
    float a = 0.f;
    #pragma unroll
    for (int j = 0; j < 27; ++j) a += src[(size_t)j*32768];
    out1[y*32768 + e] = a;
}

// ---------------- prim reduce stage 2: 8 partials + bias + squash -> u ----------------
__global__ __launch_bounds__(256)
void k_pr2(const float* __restrict__ out1, const float* __restrict__ pbias,
           float* __restrict__ u)
{
    int g = blockIdx.x*256 + threadIdx.x;      // B*2048 = 4096
    int b = g >> 11;
    int i = g & 2047;
    int cap = i >> 6;
    int s   = i & 63;
    float vals[8];
    float sq = 0.f;
    #pragma unroll
    for (int c = 0; c < 8; ++c) {
        size_t base = ((size_t)(b*256) + cap*8 + c)*64 + s;
        float a = 0.f;
        #pragma unroll
        for (int j = 0; j < 8; ++j) a += out1[(size_t)j*32768 + base];
        float x = a + pbias[cap*8 + c];
        vals[c] = x;
        sq += x*x;
    }
    float scale = (sq / (1.f + sq)) / sqrtf(sq + 1e-8f);
    #pragma unroll
    for (int c = 0; c < 8; ++c) u[(size_t)g*8 + c] = vals[c]*scale;
}

// ---------------- routing (i0 split = 8) ----------------
__global__ __launch_bounds__(256)
void k_route(const float* __restrict__ Wr, const float* __restrict__ u,
             float* __restrict__ s_buf)
{
    int j  = blockIdx.x;          // 50
    int i0 = blockIdx.y * 256;    // 8 splits
    __shared__ float us[2*256*8]; // 16 KB
    for (int idx = threadIdx.x; idx < 4096; idx += 256) {
        int b = idx >> 11;
        us[idx] = u[(size_t)b*16384 + (size_t)i0*8 + (idx & 2047)];
    }
    __syncthreads();
    int tid = threadIdx.x;
    int cc  = tid & 7;
    const float* Wj = Wr + (size_t)j*2048*512 + (size_t)i0*512;
    float a00 = 0.f, a01 = 0.f, a10 = 0.f, a11 = 0.f;
    for (int i = 0; i < 256; ++i) {
        float w0 = Wj[(size_t)i*512 + tid];
        float w1 = Wj[(size_t)i*512 + tid + 256];
        float u0 = us[i*8 + cc];
        float u1 = us[2048 + i*8 + cc];
        a00 += w0*u0; a01 += w1*u0; a10 += w0*u1; a11 += w1*u1;
    }
    __syncthreads();
    float* red = us;
    red[tid] = a00; red[256 + tid] = a01; red[512 + tid] = a10; red[768 + tid] = a11;
    __syncthreads();
    if (tid < 128) {
        int b = tid >> 6, d = tid & 63;
        const float* rb = red + b*512 + (d >> 5)*256 + (d & 31)*8;
        float s = 0.f;
        #pragma unroll
        for (int c2 = 0; c2 < 8; ++c2) s += rb[c2];
        atomicAdd(&s_buf[((size_t)b*50 + j)*64 + d], s * (1.0f/50.0f));
    }
}

// ---------------- squash v ----------------
__global__ __launch_bounds__(64)
void k_squash_v(const float* __restrict__ s_buf, float* __restrict__ v_buf)
{
    int row = blockIdx.x;
    int d   = threadIdx.x;
    float s  = s_buf[row*64 + d];
    float sq = s*s;
    #pragma unroll
    for (int o = 32; o > 0; o >>= 1) sq += __shfl_xor(sq, o);
    float scale = (sq / (1.f + sq)) / sqrtf(sq + 1e-8f);
    v_buf[row*64 + d] = s*scale;
}

// ---------------- dec1 -> fp16x2 channel-last limbs ----------------
__global__ __launch_bounds__(256)
void k_dec1(const float* __restrict__ v, const float* __restrict__ W,
            const float* __restrict__ bias, _Float16* __restrict__ d1cl)
{
    int g  = blockIdx.x*256 + threadIdx.x;  // 442368
    int co = g & 127;
    int t  = g >> 7;
    int o  = t % 1728;
    int b  = t / 1728;
    int ox = o / 144, oy = (o/12) % 12, oz = o % 12;
    int ix = ox/3, ka = ox - 3*ix;
    int iy = oy/3, kb = oy - 3*iy;
    int iz = oz/3, kc = oz - 3*iz;
    int widx = ka*9 + kb*3 + kc;
    int sidx = ix*16 + iy*4 + iz;
    float s = 0.f;
    for (int ci = 0; ci < 50; ++ci)
        s += v[((size_t)b*50 + ci)*64 + sidx] * W[((size_t)ci*128 + co)*27 + widx];
    float x = fmaxf(s + bias[co], 0.f);
    _Float16 a0, a1; split2(x, a0, a1);
    size_t base = (size_t)(b*1728 + o)*128 + co;
    d1cl[base]         = a0;
    d1cl[base + D1_PL] = a1;
}

// ---------------- dec2 MFMA, PARITY-DECOMPOSED (4-wave), per co-half ----------------
__global__ __launch_bounds__(256, 3)
void k_dec2p(const _Float16* __restrict__ d1cl, const char* __restrict__ Wb,
             const float* __restrict__ bias, float* __restrict__ out, int coBase)
{
    extern __shared__ char lds[];           // A 32KB + B 16KB
    const int tid = threadIdx.x;
    const int l   = tid & 63;
    const int w   = tid >> 6;
    const int wm  = w >> 1, wn = w & 1;
    const int cls = blockIdx.z;
    const int px  = (cls >> 2) & 1, py = (cls >> 1) & 1, pz = cls & 1;
    const int n0  = blockIdx.x * 64;        // class-local n over 3456
    const int m   = blockIdx.y;
    const int mG  = (coBase >> 7) + m;

    int cb = 0;
    for (int c = 0; c < cls; ++c) cb += 2 << __popc(c);
    const int nch = 2 << __popc(cls);

    const int nRow = tid & 63;
    const int q    = tid >> 6;
    const int nT   = n0 + nRow;
    const int b2s  = nT / 1728;
    const int rs   = nT - b2s*1728;
    const int oxh  = rs/144, oyh = (rs/12)%12, ozh = rs%12;
    const int posB = b2s*1728;
    const int bw0 = 32768 + nRow*128 + ((q*32)      ^ ((nRow&7)<<4));
    const int bw1 = 32768 + nRow*128 + ((q*32 + 16) ^ ((nRow&7)<<4));

    const int swz = (l & 7) << 4;
    const int qo  = (l >> 4) << 4;
    const int plF = (l & 15)*128 + (qo ^ (swz & 0x30)) + (swz & 0x40);

    f32x4 acc0[4][2], acc1[4][2];
    const f32x4 zz = {0.f, 0.f, 0.f, 0.f};
    #pragma unroll
    for (int a = 0; a < 4; ++a)
        #pragma unroll
        for (int b = 0; b < 2; ++b) { acc0[a][b] = zz; acc1[a][b] = zz; }

    const h8 z8 = {};
    for (int c = 0; c < nch; ++c) {
        int ti = c >> 1, ch = c & 1;
        int kd, kh, kw;
        tapDecode(cls, ti, kd, kh, kw);
        int txh = oxh + (px && kd == 0);
        int tyh = oyh + (py && kh == 0);
        int tzh = ozh + (pz && kw == 0);
        bool ok = (txh < 12) && (tyh < 12) && (tzh < 12);
        const _Float16* src = d1cl + (size_t)(posB + txh*144 + tyh*12 + tzh)*128
                                   + ch*64 + q*16;
        h8 b0a = *(const h8*)(src);
        h8 b0b = *(const h8*)(src + 8);
        h8 b1a = *(const h8*)(src + D1_PL);
        h8 b1b = *(const h8*)(src + D1_PL + 8);

        __syncthreads();
        {
            const char* wsrc = (const char*)Wb + ((size_t)(mG*54 + cb + c))*32768 + w*8192;
            #pragma unroll
            for (int i = 0; i < 8; ++i)
                gload16(wsrc + i*1024 + l*16, lds + w*8192 + i*1024);
        }
        *(h8*)(lds + bw0)         = ok ? b0a : z8;
        *(h8*)(lds + bw1)         = ok ? b0b : z8;
        *(h8*)(lds + 8192 + bw0)  = ok ? b1a : z8;
        *(h8*)(lds + 8192 + bw1)  = ok ? b1b : z8;
        __syncthreads();

        #pragma unroll
        for (int ks = 0; ks < 2; ++ks) {
            const int kx = ks ? 64 : 0;
            h8 af[2][4], bf[2][2];
            #pragma unroll
            for (int v = 0; v < 2; ++v) {
                #pragma unroll
                for (int mf = 0; mf < 4; ++mf)
                    af[v][mf] = *(const h8*)(lds + v*16384 + (wm*64 + mf*16)*128 + (plF ^ kx));
                #pragma unroll
                for (int nf = 0; nf < 2; ++nf)
                    bf[v][nf] = *(const h8*)(lds + 32768 + v*8192 + (wn*32 + nf*16)*128 + (plF ^ kx));
            }
            #pragma unroll
            for (int mf = 0; mf < 4; ++mf)
                #pragma unroll
                for (int nf = 0; nf < 2; ++nf) {
                    acc0[mf][nf] = __builtin_amdgcn_mfma_f32_16x16x32_f16(af[0][mf], bf[0][nf], acc0[mf][nf], 0,0,0);
                    acc1[mf][nf] = __builtin_amdgcn_mfma_f32_16x16x32_f16(af[0][mf], bf[1][nf], acc1[mf][nf], 0,0,0);
                    acc1[mf][nf] = __builtin_amdgcn_mfma_f32_16x16x32_f16(af[1][mf], bf[0][nf], acc1[mf][nf], 0,0,0);
                }
        }
    }

    const float s1 = 4.8828125e-04f;
    #pragma unroll
    for (int mf = 0; mf < 4; ++mf)
        #pragma unroll
        for (int nf = 0; nf < 2; ++nf) {
            f32x4 r = acc0[mf][nf] + s1*acc1[mf][nf];
            int coL = m*128 + wm*64 + mf*16 + ((l>>4)<<2);
            int coG = coBase + coL;
            int nT2 = n0 + wn*32 + nf*16 + (l&15);
            int b2  = nT2 / 1728;
            int r2  = nT2 - b2*1728;
            int ax  = r2/144, ay = (r2/12)%12, az = r2%12;
            int outIdx = b2*13824 + (2*ax + px)*576 + (2*ay + py)*24 + (2*az + pz);
            float4 v;
            v.x = fmaxf(r[0] + bias[coG + 0], 0.f);
            v.y = fmaxf(r[1] + bias[coG + 1], 0.f);
            v.z = fmaxf(r[2] + bias[coG + 2], 0.f);
            v.w = fmaxf(r[3] + bias[coG + 3], 0.f);
            *(float4*)(out + (size_t)outIdx*256 + coL) = v;
        }
}

// ---------------- final gather (per co-half) ----------------
__global__ __launch_bounds__(256)
void k_gather(const float* __restrict__ d2h, const int* __restrict__ vid,
              float* __restrict__ out, int colOff)
{
    int g  = blockIdx.x*256 + threadIdx.x;   // B*P*64 float4 units
    int qq = g & 63;
    int bp = g >> 6;
    int v  = vid[bp];
    int b  = bp >> 13;
    float4 val = *(const float4*)&d2h[((size_t)(b*N3 + v))*256 + qq*4];
    *(float4*)&out[(size_t)bp*512 + colOff + qq*4] = val;
}

extern "C" void kernel_launch(void* const* d_in, const int* in_sizes, int n_in,
                              void* d_out, int out_size, void* d_ws, size_t ws_size,
                              hipStream_t stream)
{
    (void)in_sizes; (void)n_in; (void)out_size; (void)ws_size;
    const float* pcl  = (const float*)d_in[0];
    const float* feat = (const float*)d_in[1];
    const float* c1w  = (const float*)d_in[3];
    const float* c1b  = (const float*)d_in[4];
    const float* c2w  = (const float*)d_in[5];
    const float* c2b  = (const float*)d_in[6];
    const float* pw   = (const float*)d_in[7];
    const float* pb   = (const float*)d_in[8];
    const float* rw   = (const float*)d_in[9];
    const float* d1w  = (const float*)d_in[10];
    const float* d1b_ = (const float*)d_in[11];
    const float* d2w  = (const float*)d_in[12];
    const float* d2b  = (const float*)d_in[13];

    char* ws = (char*)d_ws;
    float*     meshS  = (float*)(ws + MESHS_OFF);
    _Float16*  m16    = (_Float16*)(ws + M16_OFF);
    _Float16*  h1cl   = (_Float16*)(ws + H1CL_OFF);
    char*      Wb     = ws + WB_OFF;
    char*      Wb2c   = ws + WB2C_OFF;
    float*     h2p    = (float*)(ws + H2P_OFF);
    float*     p_part = (float*)(ws + PPART_OFF);
    float*     pr1    = (float*)(ws + PR1_OFF);
    char*      Wbd    = ws + WBD_OFF;
    float*     d2h    = (float*)(ws + D2H_OFF);
    _Float16*  d1cl   = (_Float16*)(ws + D1CL_OFF);
    int*       vid    = (int*)(ws + VID_OFF);
    float*     u_buf  = (float*)(ws + UBUF_OFF);
    float*     s_buf  = (float*)(ws + SBUF_OFF);
    float*     v_buf  = (float*)(ws + VBUF_OFF);

    k_vid<<<dim3(B_), dim3(256), 0, stream>>>(pcl, vid);

    hipMemsetAsync(meshS, 0, 14155776, stream);
    k_scatter<<<dim3(8192), dim3(256), 0, stream>>>(feat, vid, meshS);
    k_meshsplit<<<dim3(3456), dim3(256), 0, stream>>>(meshS, m16);

    // conv1
    k_splitw1<<<dim3(16000), dim3(256), 0, stream>>>(c1w, Wb);
    k_conv1<<<dim3(250, 2), dim3(256), 49152, stream>>>(m16, Wb, c1b, h1cl);

    // conv2: two half-K weight stages, 128x128 block tile, z=3 split-K -> 3 partial slabs
    k_splitw2<<<dim3(15872), dim3(256), 0, stream>>>(c2w, Wb2c, 0, 248);
    k_conv2<<<dim3(64, 2, 3), dim3(256), 65536, stream>>>(h1cl, Wb2c, h2p, 0, 248, 0);
    k_splitw2<<<dim3(16128), dim3(256), 0, stream>>>(c2w, Wb2c, 248, 252);
    k_conv2<<<dim3(64, 2, 3), dim3(256), 65536, stream>>>(h1cl, Wb2c, h2p, 248, 252, 1);
    k_h2epi<<<dim3(2048), dim3(256), 0, stream>>>(h2p, c2b);

    // primary caps: fp32 GEMM -> 216 partial slabs, then 2-stage wide reduce
    k_gemm_conv<256,9,2,16,4><<<dim3(1, 2, 216), dim3(256), 0, stream>>>(h2p, pw, p_part);
    k_pr1<<<dim3(128, 8), dim3(256), 0, stream>>>(p_part, pr1);
    k_pr2<<<dim3(16), dim3(256), 0, stream>>>(pr1, pb, u_buf);

    hipMemsetAsync(s_buf, 0, 25600, stream);
    k_route<<<dim3(50, 8), dim3(256), 0, stream>>>(rw, u_buf, s_buf);
    k_squash_v<<<dim3(100), dim3(64), 0, stream>>>(s_buf, v_buf);

    k_dec1<<<dim3(1728), dim3(256), 0, stream>>>(v_buf, d1w, d1b_, d1cl);

    // dec2 weights, parity-grouped (Wbd overlaps h2p region, dead by then)
    k_splitwd2p<<<dim3(6912), dim3(256), 0, stream>>>(d2w, Wbd);

    k_dec2p<<<dim3(54, 2, 8), dim3(256), 49152, stream>>>(d1cl, Wbd, d2b, d2h, 0);
    k_gather<<<dim3(4096), dim3(256), 0, stream>>>(d2h, vid, (float*)d_out, 0);
    k_dec2p<<<dim3(54, 2, 8), dim3(256), 49152, stream>>>(d1cl, Wbd, d2b, d2h, 256);
    k_gather<<<dim3(4096), dim3(256), 0, stream>>>(d2h, vid, (float*)d_out, 256);
}

// Round 19
// 1247.001 us; speedup vs baseline: 1.3483x; 1.0275x over previous
//
#include <hip/hip_runtime.h>
#include <cstdint>
#include <cstddef>

typedef _Float16 h8 __attribute__((ext_vector_type(8)));
typedef _Float16 h4 __attribute__((ext_vector_type(4)));
typedef float    f32x4 __attribute__((ext_vector_type(4)));

#define B_   2
#define P_   8192
#define NVOX 24
#define N3   13824

// ---- workspace layout (bytes). Peak 63.44 MB < 63.50 MB tail. ----
// A: m16@0 (14.16M) ; meshS@30,670,848 (14.16M, dead after meshsplit)
// B(conv1): m16@0, Wb@14,155,776 (16.38M -> 30,539,776), c1s@30,670,848 (32.77M -> 63,438,848)
// C(c1epi): h1cl@0 (16.38M) [m16,Wb dead]
// D(conv2): h1cl@0, Wb2c@16,384,000 (16.52M -> 32,899,072), h2p@32,899,072 (25.17M -> 58,064,896)
// E(prim):  p_part@0 (28.31M) [h1cl,Wb2c dead] ; pr1@58,064,896 (1M)
// F(dec):   Wbd@0 (10.62M), d2h@10,616,832 (28.31M -> 38,928,384), d1cl@38,928,384 (1.77M)
#define M16_OFF   0ull
#define WB_OFF    14155776ull
#define MESHS_OFF 30670848ull
#define C1S_OFF   30670848ull
#define H1CL_OFF  0ull
#define WB2C_OFF  16384000ull
#define H2P_OFF   32899072ull
#define PPART_OFF 0ull
#define PR1_OFF   58064896ull
#define WBD_OFF   0ull
#define D2H_OFF   10616832ull
#define D1CL_OFF  38928384ull
#define VID_OFF   63504384ull
#define UBUF_OFF  63700992ull
#define SBUF_OFF  63832064ull
#define VBUF_OFF  63857664ull

#define M16_PL   3538944ull     // mesh16 plane stride (elements)
#define H1_PL    4096000ull     // h1cl plane stride (elements)
#define D1_PL    442368ull      // d1cl plane stride (elements)
#define C1S_PL   4096000ull     // conv1 slab stride (elements)

// ---------------- helpers ----------------
__device__ inline void split2(float x, _Float16& a0, _Float16& a1)
{
    a0 = (_Float16)x;
    float r = x - (float)a0;
    a1 = (_Float16)(r * 2048.0f);
}

__device__ inline void gload16(const void* g, void* l)
{
    __builtin_amdgcn_global_load_lds(
        (const __attribute__((address_space(1))) char*)g,
        (__attribute__((address_space(3))) char*)l, 16, 0, 0);
}

// parity-class helpers for dec2
__device__ inline void tapDecode(int cls, int ti, int& kd, int& kh, int& kw)
{
    int px = (cls >> 2) & 1, py = (cls >> 1) & 1, pz = cls & 1;
    int tiz = pz ? (ti & 1) : 0;
    int t1  = ti >> pz;
    int tiy = py ? (t1 & 1) : 0;
    int tix = t1 >> py;
    kd = px ? tix*2 : 1;
    kh = py ? tiy*2 : 1;
    kw = pz ? tiz*2 : 1;
}

// ---------------- voxel ids ----------------
__global__ __launch_bounds__(256)
void k_vid(const float* __restrict__ pcl, int* __restrict__ vid)
{
    int b = blockIdx.x;
    const float* pb = pcl + (size_t)b * P_ * 3;
    float mn[3] = {3e38f, 3e38f, 3e38f};
    float mx[3] = {-3e38f, -3e38f, -3e38f};
    for (int p = threadIdx.x; p < P_; p += 256) {
        #pragma unroll
        for (int d = 0; d < 3; ++d) {
            float v = pb[p*3 + d];
            mn[d] = fminf(mn[d], v);
            mx[d] = fmaxf(mx[d], v);
        }
    }
    __shared__ float red[6][256];
    #pragma unroll
    for (int d = 0; d < 3; ++d) { red[d][threadIdx.x] = mn[d]; red[3+d][threadIdx.x] = mx[d]; }
    __syncthreads();
    for (int s = 128; s > 0; s >>= 1) {
        if (threadIdx.x < (unsigned)s) {
            #pragma unroll
            for (int d = 0; d < 3; ++d) {
                red[d][threadIdx.x]   = fminf(red[d][threadIdx.x],   red[d][threadIdx.x + s]);
                red[3+d][threadIdx.x] = fmaxf(red[3+d][threadIdx.x], red[3+d][threadIdx.x + s]);
            }
        }
        __syncthreads();
    }
    float mn0 = red[0][0], mn1 = red[1][0], mn2 = red[2][0];
    float dd0 = red[3][0] - mn0 + 1e-9f;
    float dd1 = red[4][0] - mn1 + 1e-9f;
    float dd2 = red[5][0] - mn2 + 1e-9f;
    for (int p = threadIdx.x; p < P_; p += 256) {
        float fx = (pb[p*3+0] - mn0) / dd0 * 24.0f;
        float fy = (pb[p*3+1] - mn1) / dd1 * 24.0f;
        float fz = (pb[p*3+2] - mn2) / dd2 * 24.0f;
        int ix = (int)floorf(fx); ix = ix < 0 ? 0 : (ix > 23 ? 23 : ix);
        int iy = (int)floorf(fy); iy = iy < 0 ? 0 : (iy > 23 ? 23 : iy);
        int iz = (int)floorf(fz); iz = iz < 0 ? 0 : (iz > 23 ? 23 : iz);
        vid[b*P_ + p] = ix*576 + iy*24 + iz;
    }
}

// ---------------- scatter-add point features -> meshS (B, N3, 128) ----------------
__global__ __launch_bounds__(256)
void k_scatter(const float* __restrict__ feat, const int* __restrict__ vid,
               float* __restrict__ meshS)
{
    int g = blockIdx.x*256 + threadIdx.x;      // B*P*C = 2,097,152
    int c  = g & 127;
    int bp = g >> 7;
    int v  = vid[bp];
    int b  = bp >> 13;
    atomicAdd(&meshS[((size_t)b*N3 + v)*128 + c], feat[g]);
}

// ---------------- mesh fp32 -> fp16x2 limb planes ----------------
__global__ __launch_bounds__(256)
void k_meshsplit(const float* __restrict__ meshS, _Float16* __restrict__ m16)
{
    int g = blockIdx.x*256 + threadIdx.x;   // 884,736 float4 groups
    int e = g*4;
    float4 a = *(const float4*)(meshS + e);
    h4 v0, v1;
    float xs[4] = {a.x, a.y, a.z, a.w};
    #pragma unroll
    for (int j = 0; j < 4; ++j) {
        _Float16 t0, t1; split2(xs[j], t0, t1);
        v0[j] = t0; v1[j] = t1;
    }
    *(h4*)(m16 + e)          = v0;
    *(h4*)(m16 + M16_PL + e) = v1;
}

// ---------------- pre-split conv1 weights ----------------
__global__ __launch_bounds__(256)
void k_splitw1(const float* __restrict__ W, char* __restrict__ Wb)
{
    int g = blockIdx.x*256 + threadIdx.x;   // 4,096,000
    int el   = g & 8191;
    int tile = g >> 13;                      // m*250 + c
    int m = tile / 250, c = tile - m*250;
    int co = el >> 6, kl = el & 63;
    int kg = c*64 + kl;
    int kid = kg >> 7, ci = kg & 127;
    float x = W[((size_t)((m*128 + co)*128 + ci))*125 + kid];
    _Float16 a0, a1; split2(x, a0, a1);
    char* dst = Wb + (size_t)tile*32768 + (co*128 + ((kl*2) ^ ((co&7)<<4)));
    *(_Float16*)(dst)         = a0;
    *(_Float16*)(dst + 16384) = a1;
}

// ---------------- pre-split conv2 weights (half-K at a time) ----------------
__global__ __launch_bounds__(256)
void k_splitw2(const float* __restrict__ W, char* __restrict__ Wb, int cBase, int NC)
{
    int g = blockIdx.x*256 + threadIdx.x;   // 2*NC*8192
    int el   = g & 8191;
    int tile = g >> 13;                      // m*NC + cl
    int m = tile / NC, cl = tile - m*NC;
    int c = cBase + cl;
    int co = el >> 6, kl = el & 63;
    int kg = c*64 + kl;
    int kid = kg >> 8, ci = kg & 255;
    float x = W[((size_t)((m*128 + co)*256 + ci))*125 + kid];
    _Float16 a0, a1; split2(x, a0, a1);
    char* dst = Wb + (size_t)tile*32768 + (co*128 + ((kl*2) ^ ((co&7)<<4)));
    *(_Float16*)(dst)         = a0;
    *(_Float16*)(dst + 16384) = a1;
}

// ---------------- pre-split dec2 weights, PARITY-GROUPED ----------------
__global__ __launch_bounds__(256)
void k_splitwd2p(const float* __restrict__ W, char* __restrict__ Wb)
{
    int g = blockIdx.x*256 + threadIdx.x;   // 216*8192 = 1,769,472
    int el   = g & 8191;
    int tile = g >> 13;                      // mG*54 + chunkG
    int mG = tile / 54, chunkG = tile - mG*54;
    int co = el >> 6, kl = el & 63;
    int rem = chunkG, cls = 0;
    for (int c = 0; c < 8; ++c) {
        int cc = 2 << __popc(c);
        if (rem < cc) { cls = c; break; }
        rem -= cc;
    }
    int k  = rem*64 + kl;
    int ti = k >> 7;
    int ci = k & 127;
    int kd, kh, kw;
    tapDecode(cls, ti, kd, kh, kw);
    int kid = kd*9 + kh*3 + kw;
    float x = W[((size_t)ci*512 + (mG*128 + co))*27 + kid];
    _Float16 a0, a1; split2(x, a0, a1);
    char* dst = Wb + (size_t)tile*32768 + (co*128 + ((kl*2) ^ ((co&7)<<4)));
    *(_Float16*)(dst)         = a0;
    *(_Float16*)(dst + 16384) = a1;
}

// ---------------- conv1 MFMA: 128M x 128N block, 4 waves (64x64), split-K z=2 ----------------
// LDS: A 32KB + B 32KB = 64KB. Output: raw fp32 partial slabs [z][n*256+co].
__global__ __launch_bounds__(256, 2)
void k_conv1(const _Float16* __restrict__ m16, const char* __restrict__ Wb,
             float* __restrict__ c1s)
{
    extern __shared__ char lds[];
    const int tid = threadIdx.x;
    const int l   = tid & 63;
    const int w   = tid >> 6;
    const int wm  = w >> 1, wn = w & 1;
    const int n0  = blockIdx.x * 128;
    const int m   = blockIdx.y;
    const int cl0 = blockIdx.z * 125;

    // B gload sources (8 per wave), inverse-swizzled per-lane addresses; 32KB B region
    const _Float16* preP[8];
    #pragma unroll
    for (int i = 0; i < 8; ++i) {
        int g   = w*8192 + i*1024 + l*16;
        int ver = g >> 14;
        int dd  = g & 16383;
        int nl  = dd >> 7;
        int lg  = (dd & 127) ^ ((nl & 7) << 4);
        int klocal = lg >> 1;
        int n  = n0 + nl;
        int b2 = n / 8000;
        int so = n - b2*8000;
        int x = so/400, y = (so/20)%20, z = so%20;
        preP[i] = m16 + (size_t)ver*M16_PL
                      + ((size_t)(b2*13824 + x*576 + y*24 + z))*128 + klocal;
    }

    const int swz = (l & 7) << 4;
    const int qo  = (l >> 4) << 4;
    const int plF = (l & 15)*128 + (qo ^ (swz & 0x30)) + (swz & 0x40);

    f32x4 acc0[4][4], acc1[4][4];
    const f32x4 zz = {0.f, 0.f, 0.f, 0.f};
    #pragma unroll
    for (int a = 0; a < 4; ++a)
        #pragma unroll
        for (int b = 0; b < 4; ++b) { acc0[a][b] = zz; acc1[a][b] = zz; }

    for (int c = cl0; c < cl0 + 125; ++c) {
        int kid = c >> 1;
        int kd = kid/25, rr = kid - kd*25, kh = rr/5, kw = rr - kh*5;
        int koff = (kd*576 + kh*24 + kw)*128 + (c & 1)*64;

        __syncthreads();
        {
            const char* wsrc = (const char*)Wb + ((size_t)(m*250 + c))*32768 + w*8192;
            #pragma unroll
            for (int i = 0; i < 8; ++i)
                gload16(wsrc + i*1024 + l*16, lds + w*8192 + i*1024);
            #pragma unroll
            for (int i = 0; i < 8; ++i)
                gload16(preP[i] + koff, lds + 32768 + w*8192 + i*1024);
        }
        __syncthreads();

        #pragma unroll
        for (int ks = 0; ks < 2; ++ks) {
            const int kx = ks ? 64 : 0;
            h8 af[2][4], bf[2][4];
            #pragma unroll
            for (int v = 0; v < 2; ++v) {
                #pragma unroll
                for (int mf = 0; mf < 4; ++mf)
                    af[v][mf] = *(const h8*)(lds + v*16384 + (wm*64 + mf*16)*128 + (plF ^ kx));
                #pragma unroll
                for (int nf = 0; nf < 4; ++nf)
                    bf[v][nf] = *(const h8*)(lds + 32768 + v*16384 + (wn*64 + nf*16)*128 + (plF ^ kx));
            }
            #pragma unroll
            for (int mf = 0; mf < 4; ++mf)
                #pragma unroll
                for (int nf = 0; nf < 4; ++nf) {
                    acc0[mf][nf] = __builtin_amdgcn_mfma_f32_16x16x32_f16(af[0][mf], bf[0][nf], acc0[mf][nf], 0,0,0);
                    acc1[mf][nf] = __builtin_amdgcn_mfma_f32_16x16x32_f16(af[0][mf], bf[1][nf], acc1[mf][nf], 0,0,0);
                    acc1[mf][nf] = __builtin_amdgcn_mfma_f32_16x16x32_f16(af[1][mf], bf[0][nf], acc1[mf][nf], 0,0,0);
                }
        }
    }

    const float s1 = 4.8828125e-04f;
    float* oz = c1s + (size_t)blockIdx.z * C1S_PL;
    #pragma unroll
    for (int mf = 0; mf < 4; ++mf)
        #pragma unroll
        for (int nf = 0; nf < 4; ++nf) {
            f32x4 r = acc0[mf][nf] + s1*acc1[mf][nf];
            int co = m*128 + wm*64 + mf*16 + ((l>>4)<<2);
            int n  = n0 + wn*64 + nf*16 + (l&15);
            *(f32x4*)(oz + (size_t)n*256 + co) = r;
        }
}

// ---------------- conv1 epilogue: combine slabs + bias + relu -> h1cl fp16x2 limbs ----------------
__global__ __launch_bounds__(256)
void k_c1epi(const float* __restrict__ c1s, const float* __restrict__ bias,
             _Float16* __restrict__ h1cl)
{
    int g = blockIdx.x*256 + threadIdx.x;   // 1,024,000 float4 groups
    int e = g*4;
    int co = e & 255;
    float4 a = *(const float4*)(c1s + e);
    float4 b = *(const float4*)(c1s + C1S_PL + e);
    float xs[4] = {a.x + b.x, a.y + b.y, a.z + b.z, a.w + b.w};
    h4 v0, v1;
    #pragma unroll
    for (int j = 0; j < 4; ++j) {
        float x = fmaxf(xs[j] + bias[co + j], 0.f);
        _Float16 t0, t1; split2(x, t0, t1);
        v0[j] = t0; v1[j] = t1;
    }
    *(h4*)(h1cl + e)         = v0;
    *(h4*)(h1cl + H1_PL + e) = v1;
}

// ---------------- conv2 MFMA: 128M x 128N block, 4 waves (64x64 each), z-split ----------------
__global__ __launch_bounds__(256, 2)
void k_conv2(const _Float16* __restrict__ h1cl, const char* __restrict__ Wb,
             float* __restrict__ h2p, int cBase, int NSt, int accum)
{
    extern __shared__ char lds[];
    const int tid = threadIdx.x;
    const int l   = tid & 63;
    const int w   = tid >> 6;
    const int wm  = w >> 1, wn = w & 1;
    const int n0  = blockIdx.x * 128;
    const int m   = blockIdx.y;
    const int per = (NSt + (int)gridDim.z - 1) / (int)gridDim.z;
    const int cl0 = blockIdx.z * per;
    const int cl1 = min(NSt, cl0 + per);

    const _Float16* preP[8];
    #pragma unroll
    for (int i = 0; i < 8; ++i) {
        int g   = w*8192 + i*1024 + l*16;
        int ver = g >> 14;
        int dd  = g & 16383;
        int nl  = dd >> 7;
        int lg  = (dd & 127) ^ ((nl & 7) << 4);
        int klocal = lg >> 1;
        int n = n0 + nl;
        int b2 = n >> 12, so = n & 4095;
        int x = so >> 8, y = (so >> 4) & 15, z = so & 15;
        preP[i] = h1cl + (size_t)ver*H1_PL
                       + ((size_t)(b2*8000 + x*400 + y*20 + z))*256 + klocal;
    }

    const int swz = (l & 7) << 4;
    const int qo  = (l >> 4) << 4;
    const int plF = (l & 15)*128 + (qo ^ (swz & 0x30)) + (swz & 0x40);

    f32x4 acc0[4][4], acc1[4][4];
    const f32x4 zz = {0.f, 0.f, 0.f, 0.f};
    #pragma unroll
    for (int a = 0; a < 4; ++a)
        #pragma unroll
        for (int b = 0; b < 4; ++b) { acc0[a][b] = zz; acc1[a][b] = zz; }

    for (int cl = cl0; cl < cl1; ++cl) {
        int cg = cBase + cl;
        int kid = cg >> 2;
        int kd = kid/25, rr = kid - kd*25, kh = rr/5, kw = rr - kh*5;
        int koff = (kd*400 + kh*20 + kw)*256 + (cg & 3)*64;

        __syncthreads();
        {
            const char* wsrc = (const char*)Wb + ((size_t)(m*NSt + cl))*32768 + w*8192;
            #pragma unroll
            for (int i = 0; i < 8; ++i)
                gload16(wsrc + i*1024 + l*16, lds + w*8192 + i*1024);
            #pragma unroll
            for (int i = 0; i < 8; ++i)
                gload16(preP[i] + koff, lds + 32768 + w*8192 + i*1024);
        }
        __syncthreads();

        #pragma unroll
        for (int ks = 0; ks < 2; ++ks) {
            const int kx = ks ? 64 : 0;
            h8 af[2][4], bf[2][4];
            #pragma unroll
            for (int v = 0; v < 2; ++v) {
                #pragma unroll
                for (int mf = 0; mf < 4; ++mf)
                    af[v][mf] = *(const h8*)(lds + v*16384 + (wm*64 + mf*16)*128 + (plF ^ kx));
                #pragma unroll
                for (int nf = 0; nf < 4; ++nf)
                    bf[v][nf] = *(const h8*)(lds + 32768 + v*16384 + (wn*64 + nf*16)*128 + (plF ^ kx));
            }
            #pragma unroll
            for (int mf = 0; mf < 4; ++mf)
                #pragma unroll
                for (int nf = 0; nf < 4; ++nf) {
                    acc0[mf][nf] = __builtin_amdgcn_mfma_f32_16x16x32_f16(af[0][mf], bf[0][nf], acc0[mf][nf], 0,0,0);
                    acc1[mf][nf] = __builtin_amdgcn_mfma_f32_16x16x32_f16(af[0][mf], bf[1][nf], acc1[mf][nf], 0,0,0);
                    acc1[mf][nf] = __builtin_amdgcn_mfma_f32_16x16x32_f16(af[1][mf], bf[0][nf], acc1[mf][nf], 0,0,0);
                }
        }
    }

    const float s1 = 4.8828125e-04f;
    float* oz = h2p + (size_t)blockIdx.z * 2097152;
    #pragma unroll
    for (int mf = 0; mf < 4; ++mf)
        #pragma unroll
        for (int nf = 0; nf < 4; ++nf) {
            f32x4 r = acc0[mf][nf] + s1*acc1[mf][nf];
            int co = m*128 + wm*64 + mf*16 + ((l>>4)<<2);
            int n  = n0 + wn*64 + nf*16 + (l&15);
            int b2 = n >> 12, so = n & 4095;
            #pragma unroll
            for (int rr = 0; rr < 4; ++rr) {
                size_t idx = ((size_t)(b2*256 + co + rr))*4096 + so;
                if (accum) oz[idx] += r[rr];
                else       oz[idx]  = r[rr];
            }
        }
}

// ---------------- h2 epilogue: slab0 += slab1 + slab2 + bias, relu (in place) ----------------
__global__ __launch_bounds__(256)
void k_h2epi(float* __restrict__ p0, const float* __restrict__ bias)
{
    int g = blockIdx.x*256 + threadIdx.x;   // 524,288 float4 groups
    int e = g*4;
    int co = (e >> 12) & 255;
    float4 a = *(const float4*)(p0 + e);
    float4 b = *(const float4*)(p0 + 2097152 + e);
    float4 c = *(const float4*)(p0 + 4194304 + e);
    float bb = bias[co];
    float4 r;
    r.x = fmaxf(a.x + b.x + c.x + bb, 0.f);
    r.y = fmaxf(a.y + b.y + c.y + bb, 0.f);
    r.z = fmaxf(a.z + b.z + c.z + bb, 0.f);
    r.w = fmaxf(a.w + b.w + c.w + bb, 0.f);
    *(float4*)(p0 + e) = r;
}

// ---------------- fp32 implicit-GEMM conv (primary caps), partial-K output slabs ----------------
template<int CIN, int KD, int STRIDE, int IND, int OUTD>
__global__ __launch_bounds__(256, 2)
void k_gemm_conv(const float* __restrict__ in, const float* __restrict__ W,
                 float* __restrict__ out)
{
    constexpr int KD2  = KD*KD;
    constexpr int K3   = KD*KD*KD;
    constexpr int IND2 = IND*IND;
    constexpr int IND3 = IND2*IND;
    constexpr int OUT2 = OUTD*OUTD;
    constexpr int OUT3 = OUT2*OUTD;
    constexpr int KTOT = CIN*K3;
    constexpr int NCH  = KTOT/16;

    const int tid  = threadIdx.x;
    const int mIdx = tid >> 4;
    const int nIdx = tid & 15;
    const int n0   = blockIdx.x * 128;
    const int co0  = blockIdx.y * 128;
    const int per  = NCH / (int)gridDim.z;
    const int c0   = blockIdx.z * per;
    const int c1   = c0 + per;

    __shared__ float As[16][132];
    __shared__ float Bs[16][132];

    const int nB    = n0 + (tid & 127);
    const int kHalf = tid >> 7;
    int bB = nB / OUT3;
    int sB = nB - bB*OUT3;
    int xB = sB / OUT2;
    int yB = (sB / OUTD) % OUTD;
    int zB = sB % OUTD;
    const float* inB = in + (size_t)bB*CIN*IND3
                          + (xB*STRIDE)*IND2 + (yB*STRIDE)*IND + (zB*STRIDE);
    const int cB  = tid & 127;
    const int qB  = cB >> 2;
    const int bpos = ((((qB & 1) << 4) | (qB >> 1)) << 2) | (cB & 3);

    const int aCo = tid >> 2;
    const int aKq = (tid & 3) * 4;
    const int qA  = aCo >> 2;
    const int apos = ((((qA & 1) << 4) | (qA >> 1)) << 2) | (aCo & 3);
    const float* Wr0 = W + (size_t)(co0 + aCo)*KTOT + aKq;
    const float* Wr1 = W + (size_t)(co0 + 64 + aCo)*KTOT + aKq;

    float acc[8][8];
    #pragma unroll
    for (int i = 0; i < 8; ++i)
        #pragma unroll
        for (int j = 0; j < 8; ++j) acc[i][j] = 0.f;

    for (int c = c0; c < c1; ++c) {
        const int kb = c*16;
        float4 a0 = *(const float4*)(Wr0 + kb);
        float4 a1 = *(const float4*)(Wr1 + kb);
        float bv[8];
        #pragma unroll
        for (int p = 0; p < 8; ++p) {
            int k  = kb + p*2 + kHalf;
            int ci = k / K3;
            int r  = k - ci*K3;
            int kd = r / KD2;
            int r2 = r - kd*KD2;
            int kh = r2 / KD;
            int kw = r2 - kh*KD;
            bv[p] = inB[ci*IND3 + kd*IND2 + kh*IND + kw];
        }
        __syncthreads();
        As[aKq+0][apos] = a0.x; As[aKq+1][apos] = a0.y;
        As[aKq+2][apos] = a0.z; As[aKq+3][apos] = a0.w;
        As[aKq+0][apos+32] = a1.x; As[aKq+1][apos+32] = a1.y;
        As[aKq+2][apos+32] = a1.z; As[aKq+3][apos+32] = a1.w;
        #pragma unroll
        for (int p = 0; p < 8; ++p) Bs[p*2 + kHalf][bpos] = bv[p];
        __syncthreads();
        #pragma unroll
        for (int kk = 0; kk < 16; ++kk) {
            float af[8], bf[8];
            *(float4*)&af[0] = *(const float4*)&As[kk][mIdx*4];
            *(float4*)&af[4] = *(const float4*)&As[kk][64 + mIdx*4];
            *(float4*)&bf[0] = *(const float4*)&Bs[kk][nIdx*4];
            *(float4*)&bf[4] = *(const float4*)&Bs[kk][64 + nIdx*4];
            #pragma unroll
            for (int i = 0; i < 8; ++i)
                #pragma unroll
                for (int j = 0; j < 8; ++j)
                    acc[i][j] += af[i]*bf[j];
        }
    }

    float* oz = out + (size_t)blockIdx.z * (2*256*OUT3);
    #pragma unroll
    for (int j = 0; j < 8; ++j) {
        int n = n0 + nIdx*8 + j;
        int b = n / OUT3;
        int s = n - b*OUT3;
        float* o = oz + ((size_t)b*256 + co0 + mIdx*8)*OUT3 + s;
        #pragma unroll
        for (int i = 0; i < 8; ++i)
            o[(size_t)i*OUT3] = acc[i][j];
    }
}

// ---------------- prim reduce stage 1: 216 slabs -> 8 partial slabs ----------------
__global__ __launch_bounds__(256)
void k_pr1(const float* __restrict__ pp, float* __restrict__ out1)
{
    int e = blockIdx.x*256 + threadIdx.x;   // 32768 elements, grid.x = 128
    int y = blockIdx.y;                      // 8 groups of 27 slabs
    const float* src = pp + (size_t)y*27*32768 + e;
    float a = 0.f;
    #pragma unroll
    for (int j = 0; j < 27; ++j) a += src[(size_t)j*32768];
    out1[y*32768 + e] = a;
}

// ---------------- prim reduce stage 2: 8 partials + bias + squash -> u ----------------
__global__ __launch_bounds__(256)
void k_pr2(const float* __restrict__ out1, const float* __restrict__ pbias,
           float* __restrict__ u)
{
    int g = blockIdx.x*256 + threadIdx.x;      // B*2048 = 4096
    int b = g >> 11;
    int i = g & 2047;
    int cap = i >> 6;
    int s   = i & 63;
    float vals[8];
    float sq = 0.f;
    #pragma unroll
    for (int c = 0; c < 8; ++c) {
        size_t base = ((size_t)(b*256) + cap*8 + c)*64 + s;
        float a = 0.f;
        #pragma unroll
        for (int j = 0; j < 8; ++j) a += out1[(size_t)j*32768 + base];
        float x = a + pbias[cap*8 + c];
        vals[c] = x;
        sq += x*x;
    }
    float scale = (sq / (1.f + sq)) / sqrtf(sq + 1e-8f);
    #pragma unroll
    for (int c = 0; c < 8; ++c) u[(size_t)g*8 + c] = vals[c]*scale;
}

// ---------------- routing (i0 split = 8) ----------------
__global__ __launch_bounds__(256)
void k_route(const float* __restrict__ Wr, const float* __restrict__ u,
             float* __restrict__ s_buf)
{
    int j  = blockIdx.x;          // 50
    int i0 = blockIdx.y * 256;    // 8 splits
    __shared__ float us[2*256*8]; // 16 KB
    for (int idx = threadIdx.x; idx < 4096; idx += 256) {
        int b = idx >> 11;
        us[idx] = u[(size_t)b*16384 + (size_t)i0*8 + (idx & 2047)];
    }
    __syncthreads();
    int tid = threadIdx.x;
    int cc  = tid & 7;
    const float* Wj = Wr + (size_t)j*2048*512 + (size_t)i0*512;
    float a00 = 0.f, a01 = 0.f, a10 = 0.f, a11 = 0.f;
    for (int i = 0; i < 256; ++i) {
        float w0 = Wj[(size_t)i*512 + tid];
        float w1 = Wj[(size_t)i*512 + tid + 256];
        float u0 = us[i*8 + cc];
        float u1 = us[2048 + i*8 + cc];
        a00 += w0*u0; a01 += w1*u0; a10 += w0*u1; a11 += w1*u1;
    }
    __syncthreads();
    float* red = us;
    red[tid] = a00; red[256 + tid] = a01; red[512 + tid] = a10; red[768 + tid] = a11;
    __syncthreads();
    if (tid < 128) {
        int b = tid >> 6, d = tid & 63;
        const float* rb = red + b*512 + (d >> 5)*256 + (d & 31)*8;
        float s = 0.f;
        #pragma unroll
        for (int c2 = 0; c2 < 8; ++c2) s += rb[c2];
        atomicAdd(&s_buf[((size_t)b*50 + j)*64 + d], s * (1.0f/50.0f));
    }
}

// ---------------- squash v ----------------
__global__ __launch_bounds__(64)
void k_squash_v(const float* __restrict__ s_buf, float* __restrict__ v_buf)
{
    int row = blockIdx.x;
    int d   = threadIdx.x;
    float s  = s_buf[row*64 + d];
    float sq = s*s;
    #pragma unroll
    for (int o = 32; o > 0; o >>= 1) sq += __shfl_xor(sq, o);
    float scale = (sq / (1.f + sq)) / sqrtf(sq + 1e-8f);
    v_buf[row*64 + d] = s*scale;
}

// ---------------- dec1 -> fp16x2 channel-last limbs ----------------
__global__ __launch_bounds__(256)
void k_dec1(const float* __restrict__ v, const float* __restrict__ W,
            const float* __restrict__ bias, _Float16* __restrict__ d1cl)
{
    int g  = blockIdx.x*256 + threadIdx.x;  // 442368
    int co = g & 127;
    int t  = g >> 7;
    int o  = t % 1728;
    int b  = t / 1728;
    int ox = o / 144, oy = (o/12) % 12, oz = o % 12;
    int ix = ox/3, ka = ox - 3*ix;
    int iy = oy/3, kb = oy - 3*iy;
    int iz = oz/3, kc = oz - 3*iz;
    int widx = ka*9 + kb*3 + kc;
    int sidx = ix*16 + iy*4 + iz;
    float s = 0.f;
    for (int ci = 0; ci < 50; ++ci)
        s += v[((size_t)b*50 + ci)*64 + sidx] * W[((size_t)ci*128 + co)*27 + widx];
    float x = fmaxf(s + bias[co], 0.f);
    _Float16 a0, a1; split2(x, a0, a1);
    size_t base = (size_t)(b*1728 + o)*128 + co;
    d1cl[base]         = a0;
    d1cl[base + D1_PL] = a1;
}

// ---------------- dec2 MFMA, PARITY-DECOMPOSED (4-wave), per co-half ----------------
__global__ __launch_bounds__(256, 3)
void k_dec2p(const _Float16* __restrict__ d1cl, const char* __restrict__ Wb,
             const float* __restrict__ bias, float* __restrict__ out, int coBase)
{
    extern __shared__ char lds[];           // A 32KB + B 16KB
    const int tid = threadIdx.x;
    const int l   = tid & 63;
    const int w   = tid >> 6;
    const int wm  = w >> 1, wn = w & 1;
    const int cls = blockIdx.z;
    const int px  = (cls >> 2) & 1, py = (cls >> 1) & 1, pz = cls & 1;
    const int n0  = blockIdx.x * 64;        // class-local n over 3456
    const int m   = blockIdx.y;
    const int mG  = (coBase >> 7) + m;

    int cb = 0;
    for (int c = 0; c < cls; ++c) cb += 2 << __popc(c);
    const int nch = 2 << __popc(cls);

    const int nRow = tid & 63;
    const int q    = tid >> 6;
    const int nT   = n0 + nRow;
    const int b2s  = nT / 1728;
    const int rs   = nT - b2s*1728;
    const int oxh  = rs/144, oyh = (rs/12)%12, ozh = rs%12;
    const int posB = b2s*1728;
    const int bw0 = 32768 + nRow*128 + ((q*32)      ^ ((nRow&7)<<4));
    const int bw1 = 32768 + nRow*128 + ((q*32 + 16) ^ ((nRow&7)<<4));

    const int swz = (l & 7) << 4;
    const int qo  = (l >> 4) << 4;
    const int plF = (l & 15)*128 + (qo ^ (swz & 0x30)) + (swz & 0x40);

    f32x4 acc0[4][2], acc1[4][2];
    const f32x4 zz = {0.f, 0.f, 0.f, 0.f};
    #pragma unroll
    for (int a = 0; a < 4; ++a)
        #pragma unroll
        for (int b = 0; b < 2; ++b) { acc0[a][b] = zz; acc1[a][b] = zz; }

    const h8 z8 = {};
    for (int c = 0; c < nch; ++c) {
        int ti = c >> 1, ch = c & 1;
        int kd, kh, kw;
        tapDecode(cls, ti, kd, kh, kw);
        int txh = oxh + (px && kd == 0);
        int tyh = oyh + (py && kh == 0);
        int tzh = ozh + (pz && kw == 0);
        bool ok = (txh < 12) && (tyh < 12) && (tzh < 12);
        const _Float16* src = d1cl + (size_t)(posB + txh*144 + tyh*12 + tzh)*128
                                   + ch*64 + q*16;
        h8 b0a = *(const h8*)(src);
        h8 b0b = *(const h8*)(src + 8);
        h8 b1a = *(const h8*)(src + D1_PL);
        h8 b1b = *(const h8*)(src + D1_PL + 8);

        __syncthreads();
        {
            const char* wsrc = (const char*)Wb + ((size_t)(mG*54 + cb + c))*32768 + w*8192;
            #pragma unroll
            for (int i = 0; i < 8; ++i)
                gload16(wsrc + i*1024 + l*16, lds + w*8192 + i*1024);
        }
        *(h8*)(lds + bw0)         = ok ? b0a : z8;
        *(h8*)(lds + bw1)         = ok ? b0b : z8;
        *(h8*)(lds + 8192 + bw0)  = ok ? b1a : z8;
        *(h8*)(lds + 8192 + bw1)  = ok ? b1b : z8;
        __syncthreads();

        #pragma unroll
        for (int ks = 0; ks < 2; ++ks) {
            const int kx = ks ? 64 : 0;
            h8 af[2][4], bf[2][2];
            #pragma unroll
            for (int v = 0; v < 2; ++v) {
                #pragma unroll
                for (int mf = 0; mf < 4; ++mf)
                    af[v][mf] = *(const h8*)(lds + v*16384 + (wm*64 + mf*16)*128 + (plF ^ kx));
                #pragma unroll
                for (int nf = 0; nf < 2; ++nf)
                    bf[v][nf] = *(const h8*)(lds + 32768 + v*8192 + (wn*32 + nf*16)*128 + (plF ^ kx));
            }
            #pragma unroll
            for (int mf = 0; mf < 4; ++mf)
                #pragma unroll
                for (int nf = 0; nf < 2; ++nf) {
                    acc0[mf][nf] = __builtin_amdgcn_mfma_f32_16x16x32_f16(af[0][mf], bf[0][nf], acc0[mf][nf], 0,0,0);
                    acc1[mf][nf] = __builtin_amdgcn_mfma_f32_16x16x32_f16(af[0][mf], bf[1][nf], acc1[mf][nf], 0,0,0);
                    acc1[mf][nf] = __builtin_amdgcn_mfma_f32_16x16x32_f16(af[1][mf], bf[0][nf], acc1[mf][nf], 0,0,0);
                }
        }
    }

    const float s1 = 4.8828125e-04f;
    #pragma unroll
    for (int mf = 0; mf < 4; ++mf)
        #pragma unroll
        for (int nf = 0; nf < 2; ++nf) {
            f32x4 r = acc0[mf][nf] + s1*acc1[mf][nf];
            int coL = m*128 + wm*64 + mf*16 + ((l>>4)<<2);
            int coG = coBase + coL;
            int nT2 = n0 + wn*32 + nf*16 + (l&15);
            int b2  = nT2 / 1728;
            int r2  = nT2 - b2*1728;
            int ax  = r2/144, ay = (r2/12)%12, az = r2%12;
            int outIdx = b2*13824 + (2*ax + px)*576 + (2*ay + py)*24 + (2*az + pz);
            float4 v;
            v.x = fmaxf(r[0] + bias[coG + 0], 0.f);
            v.y = fmaxf(r[1] + bias[coG + 1], 0.f);
            v.z = fmaxf(r[2] + bias[coG + 2], 0.f);
            v.w = fmaxf(r[3] + bias[coG + 3], 0.f);
            *(float4*)(out + (size_t)outIdx*256 + coL) = v;
        }
}

// ---------------- final gather (per co-half) ----------------
__global__ __launch_bounds__(256)
void k_gather(const float* __restrict__ d2h, const int* __restrict__ vid,
              float* __restrict__ out, int colOff)
{
    int g  = blockIdx.x*256 + threadIdx.x;   // B*P*64 float4 units
    int qq = g & 63;
    int bp = g >> 6;
    int v  = vid[bp];
    int b  = bp >> 13;
    float4 val = *(const float4*)&d2h[((size_t)(b*N3 + v))*256 + qq*4];
    *(float4*)&out[(size_t)bp*512 + colOff + qq*4] = val;
}

extern "C" void kernel_launch(void* const* d_in, const int* in_sizes, int n_in,
                              void* d_out, int out_size, void* d_ws, size_t ws_size,
                              hipStream_t stream)
{
    (void)in_sizes; (void)n_in; (void)out_size; (void)ws_size;
    const float* pcl  = (const float*)d_in[0];
    const float* feat = (const float*)d_in[1];
    const float* c1w  = (const float*)d_in[3];
    const float* c1b  = (const float*)d_in[4];
    const float* c2w  = (const float*)d_in[5];
    const float* c2b  = (const float*)d_in[6];
    const float* pw   = (const float*)d_in[7];
    const float* pb   = (const float*)d_in[8];
    const float* rw   = (const float*)d_in[9];
    const float* d1w  = (const float*)d_in[10];
    const float* d1b_ = (const float*)d_in[11];
    const float* d2w  = (const float*)d_in[12];
    const float* d2b  = (const float*)d_in[13];

    char* ws = (char*)d_ws;
    _Float16*  m16    = (_Float16*)(ws + M16_OFF);
    char*      Wb     = ws + WB_OFF;
    float*     meshS  = (float*)(ws + MESHS_OFF);
    float*     c1s    = (float*)(ws + C1S_OFF);
    _Float16*  h1cl   = (_Float16*)(ws + H1CL_OFF);
    char*      Wb2c   = ws + WB2C_OFF;
    float*     h2p    = (float*)(ws + H2P_OFF);
    float*     p_part = (float*)(ws + PPART_OFF);
    float*     pr1    = (float*)(ws + PR1_OFF);
    char*      Wbd    = ws + WBD_OFF;
    float*     d2h    = (float*)(ws + D2H_OFF);
    _Float16*  d1cl   = (_Float16*)(ws + D1CL_OFF);
    int*       vid    = (int*)(ws + VID_OFF);
    float*     u_buf  = (float*)(ws + UBUF_OFF);
    float*     s_buf  = (float*)(ws + SBUF_OFF);
    float*     v_buf  = (float*)(ws + VBUF_OFF);

    k_vid<<<dim3(B_), dim3(256), 0, stream>>>(pcl, vid);

    hipMemsetAsync(meshS, 0, 14155776, stream);
    k_scatter<<<dim3(8192), dim3(256), 0, stream>>>(feat, vid, meshS);
    k_meshsplit<<<dim3(3456), dim3(256), 0, stream>>>(meshS, m16);

    // conv1: 128x128 block tile, split-K z=2 -> fp32 slabs, then epilogue -> h1cl limbs
    k_splitw1<<<dim3(16000), dim3(256), 0, stream>>>(c1w, Wb);
    k_conv1<<<dim3(125, 2, 2), dim3(256), 65536, stream>>>(m16, Wb, c1s);
    k_c1epi<<<dim3(4000), dim3(256), 0, stream>>>(c1s, c1b, h1cl);

    // conv2: two half-K weight stages, 128x128 block tile, z=3 split-K -> 3 partial slabs
    k_splitw2<<<dim3(15872), dim3(256), 0, stream>>>(c2w, Wb2c, 0, 248);
    k_conv2<<<dim3(64, 2, 3), dim3(256), 65536, stream>>>(h1cl, Wb2c, h2p, 0, 248, 0);
    k_splitw2<<<dim3(16128), dim3(256), 0, stream>>>(c2w, Wb2c, 248, 252);
    k_conv2<<<dim3(64, 2, 3), dim3(256), 65536, stream>>>(h1cl, Wb2c, h2p, 248, 252, 1);
    k_h2epi<<<dim3(2048), dim3(256), 0, stream>>>(h2p, c2b);

    // primary caps: fp32 GEMM -> 216 partial slabs, then 2-stage wide reduce
    k_gemm_conv<256,9,2,16,4><<<dim3(1, 2, 216), dim3(256), 0, stream>>>(h2p, pw, p_part);
    k_pr1<<<dim3(128, 8), dim3(256), 0, stream>>>(p_part, pr1);
    k_pr2<<<dim3(16), dim3(256), 0, stream>>>(pr1, pb, u_buf);

    hipMemsetAsync(s_buf, 0, 25600, stream);
    k_route<<<dim3(50, 8), dim3(256), 0, stream>>>(rw, u_buf, s_buf);
    k_squash_v<<<dim3(100), dim3(64), 0, stream>>>(s_buf, v_buf);

    k_dec1<<<dim3(1728), dim3(256), 0, stream>>>(v_buf, d1w, d1b_, d1cl);

    // dec2 weights, parity-grouped (Wbd overlaps p_part region, dead by then)
    k_splitwd2p<<<dim3(6912), dim3(256), 0, stream>>>(d2w, Wbd);

    k_dec2p<<<dim3(54, 2, 8), dim3(256), 49152, stream>>>(d1cl, Wbd, d2b, d2h, 0);
    k_gather<<<dim3(4096), dim3(256), 0, stream>>>(d2h, vid, (float*)d_out, 0);
    k_dec2p<<<dim3(54, 2, 8), dim3(256), 49152, stream>>>(d1cl, Wbd, d2b, d2h, 256);
    k_gather<<<dim3(4096), dim3(256), 0, stream>>>(d2h, vid, (float*)d_out, 256);
}